// Round 3
// baseline (565.963 us; speedup 1.0000x reference)
//
#include <hip/hip_runtime.h>

typedef __attribute__((ext_vector_type(4))) float f32x4;
typedef __attribute__((ext_vector_type(16))) float f32x16;
typedef __attribute__((ext_vector_type(8))) __bf16 bf16x8;

constexpr int FD = 128;   // feature dim D = H = 128

__device__ __forceinline__ unsigned short f2bf(float f) {
  union { float f; unsigned int u; } v; v.f = f;
  unsigned int u = v.u;
  return (unsigned short)((u + 0x7fffu + ((u >> 16) & 1u)) >> 16);  // RNE
}
__device__ __forceinline__ float bf2f(unsigned short b) {
  union { unsigned int u; float f; } v; v.u = ((unsigned int)b) << 16;
  return v.f;
}
__device__ __forceinline__ f32x16 zero16() {
  f32x16 z;
#pragma unroll
  for (int i = 0; i < 16; ++i) z[i] = 0.f;
  return z;
}

// Pack a (K,128) f32 weight matrix into 32x32x16 MFMA B-fragment order, bf16:
// frag (cg = n>>5, ks = k>>4); lane = ((k>>3)&1)*32 + (n&31); e = k&7
// dst = base + ((cg*KS + ks)*64 + lane)*8 + e,  KS = K/16
__global__ void pack_weights(const float* __restrict__ mw0, const float* __restrict__ mw1,
                             const float* __restrict__ mw2, const float* __restrict__ uw0,
                             const float* __restrict__ uw1, const float* __restrict__ uw2,
                             unsigned short* __restrict__ wp) {
  int tid = blockIdx.x * 256 + threadIdx.x;   // 576*256 == 147456 exactly
  const float* src; int base, K;
  if      (tid < 49152)  { src = mw0; base = 0;      K = 384; }
  else if (tid < 65536)  { src = mw1; base = 49152;  K = 128; }
  else if (tid < 81920)  { src = mw2; base = 65536;  K = 128; }
  else if (tid < 114688) { src = uw0; base = 81920;  K = 256; }
  else if (tid < 131072) { src = uw1; base = 114688; K = 128; }
  else                   { src = uw2; base = 131072; K = 128; }
  int i = tid - base;
  int k = i >> 7, n = i & 127;
  int KS = K >> 4;
  int dst = base + (((n >> 5) * KS + (k >> 4)) * 64 + ((k >> 3) & 1) * 32 + (n & 31)) * 8 + (k & 7);
  wp[dst] = f2bf(src[i]);
}

// Edge kernel: 64 edges/block, 512 threads = 8 waves (2 row-groups x 4 col-groups),
// each wave owns a 32x32 output tile. All weight B-fragments preloaded to registers
// ONCE per block (160 VGPR); MFMA loops have zero global loads.
__global__ __launch_bounds__(512, 2)
void in_edge_kernel(const float* __restrict__ node_x, const float* __restrict__ edge_attr,
                    const int* __restrict__ eidx, const unsigned short* __restrict__ wp,
                    const float* __restrict__ b0p, const float* __restrict__ b1p,
                    const float* __restrict__ b2p, const float* __restrict__ gp,
                    const float* __restrict__ bep, float* __restrict__ agg, int E) {
  __shared__ unsigned short sA[64 * 392];   // concat tile bf16; cols 256-383 (edge_attr) stay live
  __shared__ unsigned short sC[64 * 136];   // inter-layer activation tile bf16
  __shared__ int sSrc[64], sDst[64];
  __shared__ float sMV[64][2];              // per-row mean, rstd

  const int t = threadIdx.x;
  const int e0 = blockIdx.x * 64;
  const int lane = t & 63;
  const int w = t >> 6;
  const int l31 = lane & 31, hh = lane >> 5;
  const int m0 = (w & 1) * 32;              // row-group base
  const int cg = w >> 1;                    // col-group (0..3)
  const int n0 = cg * 32;

  // ---- one-time B-fragment preload (40 independent 16B loads; overlap staging) ----
  bf16x8 B0[24], B1[8], B2[8];
#pragma unroll
  for (int ks = 0; ks < 24; ++ks)
    B0[ks] = *(const bf16x8*)(wp + (size_t)((cg * 24 + ks) * 64 + lane) * 8);
#pragma unroll
  for (int ks = 0; ks < 8; ++ks)
    B1[ks] = *(const bf16x8*)(wp + 49152 + (size_t)((cg * 8 + ks) * 64 + lane) * 8);
#pragma unroll
  for (int ks = 0; ks < 8; ++ks)
    B2[ks] = *(const bf16x8*)(wp + 65536 + (size_t)((cg * 8 + ks) * 64 + lane) * 8);

  if (t < 64)       sSrc[t] = (e0 + t < E) ? eidx[e0 + t] : 0;
  else if (t < 128) sDst[t - 64] = (e0 + t - 64 < E) ? eidx[E + e0 + t - 64] : 0;
  __syncthreads();

  // stage concat tile: 64 rows x 384 cols, as 6144 float4 over 512 threads
#pragma unroll
  for (int i = 0; i < 12; ++i) {
    int f = t + i * 512;
    int row = f / 96;
    int c4 = (f - row * 96) * 4;
    f32x4 v = {0.f, 0.f, 0.f, 0.f};
    if (e0 + row < E) {
      const float* sp;
      if (c4 < 128)      sp = node_x + (size_t)sDst[row] * FD + c4;         // x_i = x[dst]
      else if (c4 < 256) sp = node_x + (size_t)sSrc[row] * FD + (c4 - 128); // x_j = x[src]
      else               sp = edge_attr + (size_t)(e0 + row) * FD + (c4 - 256);
      v = *(const f32x4*)sp;
    }
    ushort4 o;
    o.x = f2bf(v[0]); o.y = f2bf(v[1]); o.z = f2bf(v[2]); o.w = f2bf(v[3]);
    *(ushort4*)&sA[row * 392 + c4] = o;
  }
  __syncthreads();

  const float b0v = b0p[n0 + l31], b1v = b1p[n0 + l31], b2v = b2p[n0 + l31];
  const float gv = gp[n0 + l31], bev = bep[n0 + l31];

  // ---- layer 0: K=384 ----
  f32x16 acc = zero16();
#pragma unroll
  for (int ks = 0; ks < 24; ++ks) {
    bf16x8 a = *(const bf16x8*)&sA[(m0 + l31) * 392 + ks * 16 + hh * 8];
    acc = __builtin_amdgcn_mfma_f32_32x32x16_bf16(a, B0[ks], acc, 0, 0, 0);
  }
#pragma unroll
  for (int r = 0; r < 16; ++r) {
    int rl = (r & 3) + 8 * (r >> 2) + 4 * hh;
    sC[(m0 + rl) * 136 + n0 + l31] = f2bf(fmaxf(acc[r] + b0v, 0.f));
  }
  __syncthreads();

  // ---- layer 1: K=128 ----
  acc = zero16();
#pragma unroll
  for (int ks = 0; ks < 8; ++ks) {
    bf16x8 a = *(const bf16x8*)&sC[(m0 + l31) * 136 + ks * 16 + hh * 8];
    acc = __builtin_amdgcn_mfma_f32_32x32x16_bf16(a, B1[ks], acc, 0, 0, 0);
  }
#pragma unroll
  for (int r = 0; r < 16; ++r) {
    int rl = (r & 3) + 8 * (r >> 2) + 4 * hh;
    sA[(m0 + rl) * 392 + n0 + l31] = f2bf(fmaxf(acc[r] + b1v, 0.f));  // C1 -> sA cols 0..127
  }
  __syncthreads();

  // ---- layer 2: K=128 ----
  acc = zero16();
#pragma unroll
  for (int ks = 0; ks < 8; ++ks) {
    bf16x8 a = *(const bf16x8*)&sA[(m0 + l31) * 392 + ks * 16 + hh * 8];
    acc = __builtin_amdgcn_mfma_f32_32x32x16_bf16(a, B2[ks], acc, 0, 0, 0);
  }
  // h2 = acc + b2 -> sC (bf16) for row-parallel LN stats
#pragma unroll
  for (int r = 0; r < 16; ++r) {
    int rl = (r & 3) + 8 * (r >> 2) + 4 * hh;
    sC[(m0 + rl) * 136 + n0 + l31] = f2bf(acc[r] + b2v);
  }
  __syncthreads();

  // ---- LN stats: 8 threads per row ----
  {
    int row = t >> 3, j = t & 7;
    bf16x8 v0 = *(const bf16x8*)&sC[row * 136 + j * 16];
    bf16x8 v1 = *(const bf16x8*)&sC[row * 136 + j * 16 + 8];
    float s1 = 0.f, s2 = 0.f;
#pragma unroll
    for (int q = 0; q < 8; ++q) {
      float a = (float)v0[q], b = (float)v1[q];
      s1 += a + b; s2 += a * a + b * b;
    }
#pragma unroll
    for (int m = 1; m < 8; m <<= 1) {
      s1 += __shfl_xor(s1, m, 64);
      s2 += __shfl_xor(s2, m, 64);
    }
    if (j == 0) {
      float mean = s1 * (1.f / 128.f);
      float var  = s2 * (1.f / 128.f) - mean * mean;
      sMV[row][0] = mean;
      sMV[row][1] = rsqrtf(fmaxf(var, 0.f) + 1e-5f);
    }
  }
  __syncthreads();

  // ---- epilogue: normalize + edge_attr + atomic scatter ----
#pragma unroll
  for (int r = 0; r < 16; ++r) {
    int rl = (r & 3) + 8 * (r >> 2) + 4 * hh;
    int row = m0 + rl;
    int e = e0 + row;
    if (e < E) {
      float x = acc[r] + b2v;
      float val = (x - sMV[row][0]) * sMV[row][1] * gv + bev
                + bf2f(sA[row * 392 + 256 + n0 + l31]);
      atomicAdd(agg + (size_t)sDst[row] * FD + n0 + l31, val);
    }
  }
}

// Node kernel: 64 nodes/block; concat2=[node_x | agg] -> MLP(256->128->128->128)
// -> LN -> + node_x. Same weights-in-registers structure (32 frags = 128 VGPR).
__global__ __launch_bounds__(512, 2)
void in_node_kernel(const float* __restrict__ node_x, const float* __restrict__ agg,
                    const unsigned short* __restrict__ wp,
                    const float* __restrict__ b0p, const float* __restrict__ b1p,
                    const float* __restrict__ b2p, const float* __restrict__ gp,
                    const float* __restrict__ bep, float* __restrict__ out, int N) {
  __shared__ unsigned short sA[64 * 264];   // concat2 tile bf16, stride 264
  __shared__ unsigned short sC[64 * 136];
  __shared__ float sMV[64][2];

  const int t = threadIdx.x;
  const int r0 = blockIdx.x * 64;
  const int lane = t & 63;
  const int w = t >> 6;
  const int l31 = lane & 31, hh = lane >> 5;
  const int m0 = (w & 1) * 32;
  const int cg = w >> 1;
  const int n0 = cg * 32;

  bf16x8 B0[16], B1[8], B2[8];
#pragma unroll
  for (int ks = 0; ks < 16; ++ks)
    B0[ks] = *(const bf16x8*)(wp + 81920 + (size_t)((cg * 16 + ks) * 64 + lane) * 8);
#pragma unroll
  for (int ks = 0; ks < 8; ++ks)
    B1[ks] = *(const bf16x8*)(wp + 114688 + (size_t)((cg * 8 + ks) * 64 + lane) * 8);
#pragma unroll
  for (int ks = 0; ks < 8; ++ks)
    B2[ks] = *(const bf16x8*)(wp + 131072 + (size_t)((cg * 8 + ks) * 64 + lane) * 8);

#pragma unroll
  for (int i = 0; i < 8; ++i) {            // 4096 float4
    int f = t + i * 512;
    int row = f >> 6;
    int c4 = (f & 63) * 4;
    f32x4 v = {0.f, 0.f, 0.f, 0.f};
    int r = r0 + row;
    if (r < N) {
      const float* sp = (c4 < 128) ? node_x + (size_t)r * FD + c4
                                   : agg + (size_t)r * FD + (c4 - 128);
      v = *(const f32x4*)sp;
    }
    ushort4 o;
    o.x = f2bf(v[0]); o.y = f2bf(v[1]); o.z = f2bf(v[2]); o.w = f2bf(v[3]);
    *(ushort4*)&sA[row * 264 + c4] = o;
  }
  __syncthreads();

  const float b0v = b0p[n0 + l31], b1v = b1p[n0 + l31], b2v = b2p[n0 + l31];
  const float gv = gp[n0 + l31], bev = bep[n0 + l31];

  f32x16 acc = zero16();
#pragma unroll
  for (int ks = 0; ks < 16; ++ks) {
    bf16x8 a = *(const bf16x8*)&sA[(m0 + l31) * 264 + ks * 16 + hh * 8];
    acc = __builtin_amdgcn_mfma_f32_32x32x16_bf16(a, B0[ks], acc, 0, 0, 0);
  }
#pragma unroll
  for (int r = 0; r < 16; ++r) {
    int rl = (r & 3) + 8 * (r >> 2) + 4 * hh;
    sC[(m0 + rl) * 136 + n0 + l31] = f2bf(fmaxf(acc[r] + b0v, 0.f));
  }
  __syncthreads();

  acc = zero16();
#pragma unroll
  for (int ks = 0; ks < 8; ++ks) {
    bf16x8 a = *(const bf16x8*)&sC[(m0 + l31) * 136 + ks * 16 + hh * 8];
    acc = __builtin_amdgcn_mfma_f32_32x32x16_bf16(a, B1[ks], acc, 0, 0, 0);
  }
#pragma unroll
  for (int r = 0; r < 16; ++r) {
    int rl = (r & 3) + 8 * (r >> 2) + 4 * hh;
    sA[(m0 + rl) * 264 + n0 + l31] = f2bf(fmaxf(acc[r] + b1v, 0.f));  // C1 -> sA cols 0..127
  }
  __syncthreads();

  acc = zero16();
#pragma unroll
  for (int ks = 0; ks < 8; ++ks) {
    bf16x8 a = *(const bf16x8*)&sA[(m0 + l31) * 264 + ks * 16 + hh * 8];
    acc = __builtin_amdgcn_mfma_f32_32x32x16_bf16(a, B2[ks], acc, 0, 0, 0);
  }
#pragma unroll
  for (int r = 0; r < 16; ++r) {
    int rl = (r & 3) + 8 * (r >> 2) + 4 * hh;
    sC[(m0 + rl) * 136 + n0 + l31] = f2bf(acc[r] + b2v);
  }
  __syncthreads();

  {
    int row = t >> 3, j = t & 7;
    bf16x8 v0 = *(const bf16x8*)&sC[row * 136 + j * 16];
    bf16x8 v1 = *(const bf16x8*)&sC[row * 136 + j * 16 + 8];
    float s1 = 0.f, s2 = 0.f;
#pragma unroll
    for (int q = 0; q < 8; ++q) {
      float a = (float)v0[q], b = (float)v1[q];
      s1 += a + b; s2 += a * a + b * b;
    }
#pragma unroll
    for (int m = 1; m < 8; m <<= 1) {
      s1 += __shfl_xor(s1, m, 64);
      s2 += __shfl_xor(s2, m, 64);
    }
    if (j == 0) {
      float mean = s1 * (1.f / 128.f);
      float var  = s2 * (1.f / 128.f) - mean * mean;
      sMV[row][0] = mean;
      sMV[row][1] = rsqrtf(fmaxf(var, 0.f) + 1e-5f);
    }
  }
  __syncthreads();

#pragma unroll
  for (int r = 0; r < 16; ++r) {
    int rl = (r & 3) + 8 * (r >> 2) + 4 * hh;
    int row = m0 + rl;
    int rr = r0 + row;
    if (rr < N) {
      float x = acc[r] + b2v;
      out[(size_t)rr * FD + n0 + l31] =
          (x - sMV[row][0]) * sMV[row][1] * gv + bev + node_x[(size_t)rr * FD + n0 + l31];
    }
  }
}

extern "C" void kernel_launch(void* const* d_in, const int* in_sizes, int n_in,
                              void* d_out, int out_size, void* d_ws, size_t ws_size,
                              hipStream_t stream) {
  const float* node_x    = (const float*)d_in[0];
  const float* edge_attr = (const float*)d_in[1];
  const int*   eidx      = (const int*)d_in[2];
  const int N = in_sizes[0] / FD;
  const int E = in_sizes[1] / FD;

  float* agg = (float*)d_ws;                                         // [N][128] f32
  unsigned short* wp = (unsigned short*)((char*)d_ws + (size_t)N * FD * sizeof(float));

  (void)hipMemsetAsync(agg, 0, (size_t)N * FD * sizeof(float), stream);
  pack_weights<<<576, 256, 0, stream>>>(
      (const float*)d_in[3], (const float*)d_in[5], (const float*)d_in[7],
      (const float*)d_in[11], (const float*)d_in[13], (const float*)d_in[15], wp);
  in_edge_kernel<<<(E + 63) / 64, 512, 0, stream>>>(
      node_x, edge_attr, eidx, wp,
      (const float*)d_in[4], (const float*)d_in[6], (const float*)d_in[8],
      (const float*)d_in[9], (const float*)d_in[10], agg, E);
  in_node_kernel<<<(N + 63) / 64, 512, 0, stream>>>(
      node_x, agg, wp,
      (const float*)d_in[12], (const float*)d_in[14], (const float*)d_in[16],
      (const float*)d_in[17], (const float*)d_in[18], (float*)d_out, N);
}

// Round 4
// 381.168 us; speedup vs baseline: 1.4848x; 1.4848x over previous
//
#include <hip/hip_runtime.h>

typedef __attribute__((ext_vector_type(4))) float f32x4;
typedef __attribute__((ext_vector_type(8))) __bf16 bf16x8;

constexpr int FD = 128;   // feature dim D = H = 128

__device__ __forceinline__ unsigned short f2bf(float f) {
  union { float f; unsigned int u; } v; v.f = f;
  unsigned int u = v.u;
  return (unsigned short)((u + 0x7fffu + ((u >> 16) & 1u)) >> 16);  // RNE
}
__device__ __forceinline__ float bf2f(unsigned short b) {
  union { unsigned int u; float f; } v; v.u = ((unsigned int)b) << 16;
  return v.f;
}
__device__ __forceinline__ uint4 pack8(const float* v) {
  uint4 r;
  r.x = (unsigned)f2bf(v[0]) | ((unsigned)f2bf(v[1]) << 16);
  r.y = (unsigned)f2bf(v[2]) | ((unsigned)f2bf(v[3]) << 16);
  r.z = (unsigned)f2bf(v[4]) | ((unsigned)f2bf(v[5]) << 16);
  r.w = (unsigned)f2bf(v[6]) | ((unsigned)f2bf(v[7]) << 16);
  return r;
}

// Pack a (K,128) f32 weight matrix into 16x16x32 MFMA B-fragment order, bf16:
// dst[((nt*KS + ks)*64 + lane)*8 + e] = W[k][n]
//   nt = n>>4, ks = k>>5, lane = ((k>>3)&3)*16 + (n&15), e = k&7
__global__ void pack_weights(const float* __restrict__ mw0, const float* __restrict__ mw1,
                             const float* __restrict__ mw2, const float* __restrict__ uw0,
                             const float* __restrict__ uw1, const float* __restrict__ uw2,
                             unsigned short* __restrict__ wp) {
  int tid = blockIdx.x * 256 + threadIdx.x;   // 576*256 == 147456 exactly
  const float* src; int base, K;
  if      (tid < 49152)  { src = mw0; base = 0;      K = 384; }
  else if (tid < 65536)  { src = mw1; base = 49152;  K = 128; }
  else if (tid < 81920)  { src = mw2; base = 65536;  K = 128; }
  else if (tid < 114688) { src = uw0; base = 81920;  K = 256; }
  else if (tid < 131072) { src = uw1; base = 114688; K = 128; }
  else                   { src = uw2; base = 131072; K = 128; }
  int i = tid - base;
  int k = i >> 7, n = i & 127;
  int KS = K >> 5;
  int dst = base + (((n >> 4) * KS + (k >> 5)) * 64 + ((k >> 3) & 3) * 16 + (n & 15)) * 8 + (k & 7);
  wp[dst] = f2bf(src[i]);
}

// One MLP layer on a 64-row tile: acc[4] (f32x4) += A[64xK](LDS bf16) @ Wpacked[Kx128].
// B fragments loaded directly from global (160KB total, L1/L2-resident).
template<int KSTEPS>
__device__ __forceinline__ void mfma_layer(
    const unsigned short* __restrict__ wsrc,
    const unsigned short* sAsrc, int strideA, f32x4* acc,
    int lane, int m0, int c0hi, int g16, int ln) {
#pragma unroll
  for (int ks = 0; ks < KSTEPS; ++ks) {
    bf16x8 a = *(const bf16x8*)&sAsrc[(m0 + ln) * strideA + ks * 32 + g16 * 8];
#pragma unroll
    for (int nf = 0; nf < 4; ++nf) {
      bf16x8 b = *(const bf16x8*)(wsrc + (size_t)(((c0hi + nf) * KSTEPS + ks) * 64 + lane) * 8);
      acc[nf] = __builtin_amdgcn_mfma_f32_16x16x32_bf16(a, b, acc[nf], 0, 0, 0);
    }
  }
}

// Edge kernel: 64 edges/block, 512 threads (8 waves: 4 row-groups x 2 col-groups).
// concat=[x_dst | x_src | edge_attr] -> MLP(384->128->128->128) -> LN -> +edge_attr.
// use_sort: write bf16 row to msg[e] and thread edge onto dst's linked list.
// else:     f32 atomicAdd into agg[dst] (fallback if workspace too small).
__global__ __launch_bounds__(512, 4)
void in_edge_kernel(const float* __restrict__ node_x, const float* __restrict__ edge_attr,
                    const int* __restrict__ eidx, const unsigned short* __restrict__ wp,
                    const float* __restrict__ b0p, const float* __restrict__ b1p,
                    const float* __restrict__ b2p, const float* __restrict__ gp,
                    const float* __restrict__ bep,
                    unsigned short* __restrict__ msg, int* __restrict__ head,
                    int* __restrict__ nxt, float* __restrict__ agg,
                    int use_sort, int E) {
  __shared__ unsigned short sA[64 * 392];   // concat tile bf16; cols 256-383 (edge_attr) stay live
  __shared__ unsigned short sC[64 * 136];   // inter-layer activation / h2 tile bf16
  __shared__ int sSrc[64], sDst[64];
  __shared__ float sG[128], sB[128];

  const int t = threadIdx.x;
  const int e0 = blockIdx.x * 64;

  if (t < 64) {
    sSrc[t] = (e0 + t < E) ? eidx[e0 + t] : 0;
  } else if (t < 128) {
    int r = t - 64;
    int e = e0 + r;
    int d = (e < E) ? eidx[E + e] : 0;
    sDst[r] = d;
    if (use_sort && e < E) nxt[e] = atomicExch(&head[d], e);   // linked-list build
  } else if (t < 256) {
    sG[t - 128] = gp[t - 128];
  } else if (t < 384) {
    sB[t - 256] = bep[t - 256];
  }
  __syncthreads();

  // stage concat tile: 64 rows x 384 cols, as 6144 float4 over 512 threads
#pragma unroll
  for (int i = 0; i < 12; ++i) {
    int f = t + i * 512;
    int row = f / 96;
    int c4 = (f - row * 96) * 4;
    f32x4 v = {0.f, 0.f, 0.f, 0.f};
    if (e0 + row < E) {
      const float* sp;
      if (c4 < 128)      sp = node_x + (size_t)sDst[row] * FD + c4;         // x_i = x[dst]
      else if (c4 < 256) sp = node_x + (size_t)sSrc[row] * FD + (c4 - 128); // x_j = x[src]
      else               sp = edge_attr + (size_t)(e0 + row) * FD + (c4 - 256);
      v = *(const f32x4*)sp;
    }
    ushort4 o;
    o.x = f2bf(v[0]); o.y = f2bf(v[1]); o.z = f2bf(v[2]); o.w = f2bf(v[3]);
    *(ushort4*)&sA[row * 392 + c4] = o;
  }
  __syncthreads();

  const int lane = t & 63, w = t >> 6;
  const int m0 = (w & 3) * 16;        // row-group base
  const int c0hi = (w >> 2) * 4;      // nt base (col-group * 4)
  const int c0 = c0hi * 16;
  const int g16 = lane >> 4, ln = lane & 15;

  float b0v[4], b1v[4], b2v[4];
#pragma unroll
  for (int nf = 0; nf < 4; ++nf) {
    int col = c0 + nf * 16 + ln;
    b0v[nf] = b0p[col]; b1v[nf] = b1p[col]; b2v[nf] = b2p[col];
  }

  f32x4 acc[4];
#pragma unroll
  for (int nf = 0; nf < 4; ++nf) acc[nf] = (f32x4){0.f, 0.f, 0.f, 0.f};

  mfma_layer<12>(wp, sA, 392, acc, lane, m0, c0hi, g16, ln);

#pragma unroll
  for (int nf = 0; nf < 4; ++nf)
#pragma unroll
    for (int ri = 0; ri < 4; ++ri) {
      float v = acc[nf][ri] + b0v[nf];
      sC[(m0 + g16 * 4 + ri) * 136 + c0 + nf * 16 + ln] = f2bf(fmaxf(v, 0.f));
      acc[nf][ri] = 0.f;
    }
  __syncthreads();

  mfma_layer<4>(wp + 49152, sC, 136, acc, lane, m0, c0hi, g16, ln);

  // C1 -> sA cols 0..127 (layer-0 region dead; edge_attr cols 256+ preserved)
#pragma unroll
  for (int nf = 0; nf < 4; ++nf)
#pragma unroll
    for (int ri = 0; ri < 4; ++ri) {
      float v = acc[nf][ri] + b1v[nf];
      sA[(m0 + g16 * 4 + ri) * 392 + c0 + nf * 16 + ln] = f2bf(fmaxf(v, 0.f));
      acc[nf][ri] = 0.f;
    }
  __syncthreads();

  mfma_layer<4>(wp + 65536, sA, 392, acc, lane, m0, c0hi, g16, ln);

  // h2 = acc + b2 -> sC (bf16)
#pragma unroll
  for (int nf = 0; nf < 4; ++nf)
#pragma unroll
    for (int ri = 0; ri < 4; ++ri)
      sC[(m0 + g16 * 4 + ri) * 136 + c0 + nf * 16 + ln] = f2bf(acc[nf][ri] + b2v[nf]);
  __syncthreads();

  // ---- fused LN stats + epilogue, row-wise (8 threads per row) ----
  {
    int row = t >> 3, j = t & 7;
    bf16x8 v0 = *(const bf16x8*)&sC[row * 136 + j * 16];
    bf16x8 v1 = *(const bf16x8*)&sC[row * 136 + j * 16 + 8];
    float s1 = 0.f, s2 = 0.f;
#pragma unroll
    for (int q = 0; q < 8; ++q) {
      float a = (float)v0[q], b = (float)v1[q];
      s1 += a + b; s2 += a * a + b * b;
    }
#pragma unroll
    for (int m = 1; m < 8; m <<= 1) {
      s1 += __shfl_xor(s1, m, 64);
      s2 += __shfl_xor(s2, m, 64);
    }
    float mean = s1 * (1.f / 128.f);
    float var  = s2 * (1.f / 128.f) - mean * mean;
    float rstd = rsqrtf(fmaxf(var, 0.f) + 1e-5f);

    int e = e0 + row;
    if (e < E) {
      bf16x8 ea0 = *(const bf16x8*)&sA[row * 392 + 256 + j * 16];
      bf16x8 ea1 = *(const bf16x8*)&sA[row * 392 + 256 + j * 16 + 8];
      float val[16];
#pragma unroll
      for (int q = 0; q < 8; ++q) {
        val[q]     = ((float)v0[q] - mean) * rstd * sG[j * 16 + q]     + sB[j * 16 + q]     + (float)ea0[q];
        val[8 + q] = ((float)v1[q] - mean) * rstd * sG[j * 16 + 8 + q] + sB[j * 16 + 8 + q] + (float)ea1[q];
      }
      if (use_sort) {
        uint4* dst = (uint4*)(msg + (size_t)e * FD + j * 16);
        dst[0] = pack8(val);
        dst[1] = pack8(val + 8);
      } else {
        float* ap = agg + (size_t)sDst[row] * FD + j * 16;
#pragma unroll
        for (int q = 0; q < 16; ++q) atomicAdd(ap + q, val[q]);
      }
    }
  }
}

// Node kernel: 64 nodes/block; concat2=[node_x | agg] -> MLP(256->128->128->128)
// -> LN -> + node_x. agg gathered by walking the dst linked list (f32 sum of bf16
// msg rows), or read from f32 agg in fallback mode.
__global__ __launch_bounds__(512, 4)
void in_node_kernel(const float* __restrict__ node_x,
                    const unsigned short* __restrict__ msg, const int* __restrict__ head,
                    const int* __restrict__ nxt, const float* __restrict__ agg,
                    const unsigned short* __restrict__ wp,
                    const float* __restrict__ b0p, const float* __restrict__ b1p,
                    const float* __restrict__ b2p, const float* __restrict__ gp,
                    const float* __restrict__ bep, float* __restrict__ out,
                    int use_sort, int N) {
  __shared__ unsigned short sA[64 * 264];   // concat2 tile bf16, stride 264
  __shared__ unsigned short sC[64 * 136];
  __shared__ float sG[128], sB[128];

  const int t = threadIdx.x;
  const int r0 = blockIdx.x * 64;

  if (t < 128)      sG[t] = gp[t];
  else if (t < 256) sB[t - 128] = bep[t - 128];

  // stage node_x cols 0..127 (2048 float4)
#pragma unroll
  for (int i = 0; i < 4; ++i) {
    int f = t + i * 512;
    int row = f >> 5;
    int c4 = (f & 31) * 4;
    int r = r0 + row;
    f32x4 v = {0.f, 0.f, 0.f, 0.f};
    if (r < N) v = *(const f32x4*)(node_x + (size_t)r * FD + c4);
    ushort4 o;
    o.x = f2bf(v[0]); o.y = f2bf(v[1]); o.z = f2bf(v[2]); o.w = f2bf(v[3]);
    *(ushort4*)&sA[row * 264 + c4] = o;
  }

  // stage agg cols 128..255: 8 threads per node, 16 cols each
  {
    int row = t >> 3, j = t & 7;
    int node = r0 + row;
    float a[16];
#pragma unroll
    for (int q = 0; q < 16; ++q) a[q] = 0.f;
    if (node < N) {
      if (use_sort) {
        int e = head[node];
        while (e >= 0) {
          int ne = nxt[e];
          bf16x8 m0 = *(const bf16x8*)(msg + (size_t)e * FD + j * 16);
          bf16x8 m1 = *(const bf16x8*)(msg + (size_t)e * FD + j * 16 + 8);
#pragma unroll
          for (int q = 0; q < 8; ++q) { a[q] += (float)m0[q]; a[8 + q] += (float)m1[q]; }
          e = ne;
        }
      } else {
        const float* ap = agg + (size_t)node * FD + j * 16;
#pragma unroll
        for (int q4 = 0; q4 < 4; ++q4) {
          f32x4 u = *(const f32x4*)(ap + q4 * 4);
#pragma unroll
          for (int q = 0; q < 4; ++q) a[q4 * 4 + q] = u[q];
        }
      }
    }
    uint4* dst = (uint4*)&sA[row * 264 + 128 + j * 16];
    dst[0] = pack8(a);
    dst[1] = pack8(a + 8);
  }
  __syncthreads();

  const int lane = t & 63, w = t >> 6;
  const int m0 = (w & 3) * 16;
  const int c0hi = (w >> 2) * 4;
  const int c0 = c0hi * 16;
  const int g16 = lane >> 4, ln = lane & 15;

  float b0v[4], b1v[4], b2v[4];
#pragma unroll
  for (int nf = 0; nf < 4; ++nf) {
    int col = c0 + nf * 16 + ln;
    b0v[nf] = b0p[col]; b1v[nf] = b1p[col]; b2v[nf] = b2p[col];
  }

  f32x4 acc[4];
#pragma unroll
  for (int nf = 0; nf < 4; ++nf) acc[nf] = (f32x4){0.f, 0.f, 0.f, 0.f};

  mfma_layer<8>(wp + 81920, sA, 264, acc, lane, m0, c0hi, g16, ln);

#pragma unroll
  for (int nf = 0; nf < 4; ++nf)
#pragma unroll
    for (int ri = 0; ri < 4; ++ri) {
      float v = acc[nf][ri] + b0v[nf];
      sC[(m0 + g16 * 4 + ri) * 136 + c0 + nf * 16 + ln] = f2bf(fmaxf(v, 0.f));
      acc[nf][ri] = 0.f;
    }
  __syncthreads();

  mfma_layer<4>(wp + 114688, sC, 136, acc, lane, m0, c0hi, g16, ln);

#pragma unroll
  for (int nf = 0; nf < 4; ++nf)
#pragma unroll
    for (int ri = 0; ri < 4; ++ri) {
      float v = acc[nf][ri] + b1v[nf];
      sA[(m0 + g16 * 4 + ri) * 264 + c0 + nf * 16 + ln] = f2bf(fmaxf(v, 0.f));  // C1 -> sA
      acc[nf][ri] = 0.f;
    }
  __syncthreads();

  mfma_layer<4>(wp + 131072, sA, 264, acc, lane, m0, c0hi, g16, ln);

#pragma unroll
  for (int nf = 0; nf < 4; ++nf)
#pragma unroll
    for (int ri = 0; ri < 4; ++ri)
      sC[(m0 + g16 * 4 + ri) * 136 + c0 + nf * 16 + ln] = f2bf(acc[nf][ri] + b2v[nf]);
  __syncthreads();

  // ---- fused LN stats + residual + store, row-wise ----
  {
    int row = t >> 3, j = t & 7;
    bf16x8 v0 = *(const bf16x8*)&sC[row * 136 + j * 16];
    bf16x8 v1 = *(const bf16x8*)&sC[row * 136 + j * 16 + 8];
    float s1 = 0.f, s2 = 0.f;
#pragma unroll
    for (int q = 0; q < 8; ++q) {
      float a = (float)v0[q], b = (float)v1[q];
      s1 += a + b; s2 += a * a + b * b;
    }
#pragma unroll
    for (int m = 1; m < 8; m <<= 1) {
      s1 += __shfl_xor(s1, m, 64);
      s2 += __shfl_xor(s2, m, 64);
    }
    float mean = s1 * (1.f / 128.f);
    float var  = s2 * (1.f / 128.f) - mean * mean;
    float rstd = rsqrtf(fmaxf(var, 0.f) + 1e-5f);

    int node = r0 + row;
    if (node < N) {
      float o[16];
#pragma unroll
      for (int q = 0; q < 8; ++q) {
        o[q]     = ((float)v0[q] - mean) * rstd * sG[j * 16 + q]     + sB[j * 16 + q];
        o[8 + q] = ((float)v1[q] - mean) * rstd * sG[j * 16 + 8 + q] + sB[j * 16 + 8 + q];
      }
      const float* xr = node_x + (size_t)node * FD + j * 16;
      float* orow = out + (size_t)node * FD + j * 16;
#pragma unroll
      for (int q4 = 0; q4 < 4; ++q4) {
        f32x4 x = *(const f32x4*)(xr + q4 * 4);
        f32x4 wv;
#pragma unroll
        for (int q = 0; q < 4; ++q) wv[q] = o[q4 * 4 + q] + x[q];
        *(f32x4*)(orow + q4 * 4) = wv;
      }
    }
  }
}

extern "C" void kernel_launch(void* const* d_in, const int* in_sizes, int n_in,
                              void* d_out, int out_size, void* d_ws, size_t ws_size,
                              hipStream_t stream) {
  const float* node_x    = (const float*)d_in[0];
  const float* edge_attr = (const float*)d_in[1];
  const int*   eidx      = (const int*)d_in[2];
  const int N = in_sizes[0] / FD;
  const int E = in_sizes[1] / FD;

  char* ws = (char*)d_ws;
  unsigned short* wp = (unsigned short*)ws;                 // 294,912 B
  const size_t wpB = 294912;
  const size_t headOff = wpB;
  const size_t nextOff = headOff + (((size_t)N * 4 + 255) & ~(size_t)255);
  const size_t msgOff  = nextOff + (((size_t)E * 4 + 255) & ~(size_t)255);
  const size_t need    = msgOff + (size_t)E * FD * 2;

  int use_sort = (ws_size >= need) ? 1 : 0;
  int* head = nullptr; int* nxt = nullptr;
  unsigned short* msg = nullptr; float* agg = nullptr;

  if (use_sort) {
    head = (int*)(ws + headOff);
    nxt  = (int*)(ws + nextOff);
    msg  = (unsigned short*)(ws + msgOff);
    (void)hipMemsetAsync(head, 0xFF, (size_t)N * 4, stream);   // head = -1
  } else {
    agg = (float*)(ws + wpB);
    (void)hipMemsetAsync(agg, 0, (size_t)N * FD * sizeof(float), stream);
  }

  pack_weights<<<576, 256, 0, stream>>>(
      (const float*)d_in[3], (const float*)d_in[5], (const float*)d_in[7],
      (const float*)d_in[11], (const float*)d_in[13], (const float*)d_in[15], wp);
  in_edge_kernel<<<(E + 63) / 64, 512, 0, stream>>>(
      node_x, edge_attr, eidx, wp,
      (const float*)d_in[4], (const float*)d_in[6], (const float*)d_in[8],
      (const float*)d_in[9], (const float*)d_in[10],
      msg, head, nxt, agg, use_sort, E);
  in_node_kernel<<<(N + 63) / 64, 512, 0, stream>>>(
      node_x, msg, head, nxt, agg, wp,
      (const float*)d_in[12], (const float*)d_in[14], (const float*)d_in[16],
      (const float*)d_in[17], (const float*)d_in[18], (float*)d_out, use_sort, N);
}

// Round 5
// 322.515 us; speedup vs baseline: 1.7548x; 1.1819x over previous
//
#include <hip/hip_runtime.h>

typedef __attribute__((ext_vector_type(4))) float f32x4;
typedef __attribute__((ext_vector_type(8))) __bf16 bf16x8;

constexpr int FD = 128;   // feature dim D = H = 128

__device__ __forceinline__ uint4 pack8(const float* v) {
  union { __bf16 h[8]; uint4 u; } cv;
#pragma unroll
  for (int q = 0; q < 8; ++q) cv.h[q] = (__bf16)v[q];
  return cv.u;
}
__device__ __forceinline__ unsigned int pack2(float a, float b) {
  union { __bf16 h[2]; unsigned int u; } cv;
  cv.h[0] = (__bf16)a; cv.h[1] = (__bf16)b;
  return cv.u;
}

// Pack a (K,128) f32 weight matrix into 16x16x32 MFMA B-fragment order, bf16:
// dst[((nt*KS + ks)*64 + lane)*8 + e] = W[k][n]
//   nt = n>>4, ks = k>>5, lane = ((k>>3)&3)*16 + (n&15), e = k&7
__global__ void pack_weights(const float* __restrict__ mw0, const float* __restrict__ mw1,
                             const float* __restrict__ mw2, const float* __restrict__ uw0,
                             const float* __restrict__ uw1, const float* __restrict__ uw2,
                             unsigned short* __restrict__ wp) {
  int tid = blockIdx.x * 256 + threadIdx.x;   // 576*256 == 147456 exactly
  const float* src; int base, K;
  if      (tid < 49152)  { src = mw0; base = 0;      K = 384; }
  else if (tid < 65536)  { src = mw1; base = 49152;  K = 128; }
  else if (tid < 81920)  { src = mw2; base = 65536;  K = 128; }
  else if (tid < 114688) { src = uw0; base = 81920;  K = 256; }
  else if (tid < 131072) { src = uw1; base = 114688; K = 128; }
  else                   { src = uw2; base = 131072; K = 128; }
  int i = tid - base;
  int k = i >> 7, n = i & 127;
  int KS = K >> 5;
  int dst = base + (((n >> 4) * KS + (k >> 5)) * 64 + ((k >> 3) & 3) * 16 + (n & 15)) * 8 + (k & 7);
  union { __bf16 h; unsigned short s; } cv; cv.h = (__bf16)src[i];
  wp[dst] = cv.s;
}

// Layer with B streamed from global (L2-resident; each fragment loaded by exactly
// ONE wave per block). Wave = 64 rows x 16 cols: 4 m-frags share each b-frag.
template<int KSTEPS>
__device__ __forceinline__ void mfma_gB(const unsigned short* __restrict__ wsrc,
                                        const unsigned short* sAsrc, int strideA,
                                        f32x4* acc, int w, int lane, int g16, int ln) {
#pragma unroll
  for (int ks = 0; ks < KSTEPS; ++ks) {
    bf16x8 b = *(const bf16x8*)(wsrc + (size_t)((w * KSTEPS + ks) * 64 + lane) * 8);
#pragma unroll
    for (int m = 0; m < 4; ++m) {
      bf16x8 a = *(const bf16x8*)&sAsrc[(m * 16 + ln) * strideA + ks * 32 + g16 * 8];
      acc[m] = __builtin_amdgcn_mfma_f32_16x16x32_bf16(a, b, acc[m], 0, 0, 0);
    }
  }
}

// Layer with B already in registers (zero global loads).
template<int KSTEPS>
__device__ __forceinline__ void mfma_rB(const bf16x8* B,
                                        const unsigned short* sAsrc, int strideA,
                                        f32x4* acc, int g16, int ln) {
#pragma unroll
  for (int ks = 0; ks < KSTEPS; ++ks) {
#pragma unroll
    for (int m = 0; m < 4; ++m) {
      bf16x8 a = *(const bf16x8*)&sAsrc[(m * 16 + ln) * strideA + ks * 32 + g16 * 8];
      acc[m] = __builtin_amdgcn_mfma_f32_16x16x32_bf16(a, B[ks], acc[m], 0, 0, 0);
    }
  }
}

// Store per-wave 64x16 tile (+bias, optional relu) as bf16 into [64][stride] LDS tile.
template<bool RELU>
__device__ __forceinline__ void store_tile(unsigned short* sDst, int stride,
                                           const f32x4* acc, float bias, int col, int g16) {
#pragma unroll
  for (int m = 0; m < 4; ++m)
#pragma unroll
    for (int ri = 0; ri < 4; ++ri) {
      float v = acc[m][ri] + bias;
      if (RELU) v = fmaxf(v, 0.f);
      union { __bf16 h; unsigned short s; } cv; cv.h = (__bf16)v;
      sDst[(m * 16 + g16 * 4 + ri) * stride + col] = cv.s;
    }
}

// Edge kernel: 64 edges/block, 512 threads = 8 waves, each wave owns cols w*16..w*16+15
// for ALL 64 rows. concat=[x_dst | x_src | edge_attr] -> MLP(384->128->128->128)
// -> LN -> +edge_attr -> msg[e] (bf16) + linked list (use_sort) or atomicAdd fallback.
__global__ __launch_bounds__(512, 4)
void in_edge_kernel(const float* __restrict__ node_x, const float* __restrict__ edge_attr,
                    const int* __restrict__ eidx, const unsigned short* __restrict__ wp,
                    const float* __restrict__ b0p, const float* __restrict__ b1p,
                    const float* __restrict__ b2p, const float* __restrict__ gp,
                    const float* __restrict__ bep,
                    unsigned short* __restrict__ msg, int* __restrict__ head,
                    int* __restrict__ nxt, float* __restrict__ agg,
                    int use_sort, int E) {
  __shared__ unsigned short sA[64 * 392];   // concat tile bf16; cols 256-383 (edge_attr) stay live
  __shared__ unsigned short sC[64 * 136];   // inter-layer activation / h2 tile bf16
  __shared__ int sSrc[64], sDst[64];
  __shared__ float sG[128], sB[128];

  const int t = threadIdx.x;
  const int e0 = blockIdx.x * 64;
  const int lane = t & 63, w = t >> 6;
  const int ln = lane & 15, g16 = lane >> 4;
  const int col = w * 16 + ln;

  // preload layer-1/2 B fragments into registers (overlaps index/param staging)
  bf16x8 B1r[4], B2r[4];
#pragma unroll
  for (int ks = 0; ks < 4; ++ks)
    B1r[ks] = *(const bf16x8*)(wp + 49152 + (size_t)((w * 4 + ks) * 64 + lane) * 8);
#pragma unroll
  for (int ks = 0; ks < 4; ++ks)
    B2r[ks] = *(const bf16x8*)(wp + 65536 + (size_t)((w * 4 + ks) * 64 + lane) * 8);

  if (t < 64) {
    sSrc[t] = (e0 + t < E) ? eidx[e0 + t] : 0;
  } else if (t < 128) {
    int r = t - 64;
    int e = e0 + r;
    int d = (e < E) ? eidx[E + e] : 0;
    sDst[r] = d;
    if (use_sort && e < E) nxt[e] = atomicExch(&head[d], e);   // linked-list build
  } else if (t < 256) {
    sG[t - 128] = gp[t - 128];
  } else if (t < 384) {
    sB[t - 256] = bep[t - 256];
  }
  __syncthreads();

  // stage concat tile: 192 wave-uniform 128-float segments (type is compile-time,
  // row is wave-uniform -> no divergence, no integer division; float2/lane).
#pragma unroll
  for (int it = 0; it < 24; ++it) {
    const int type = it >> 3;                  // 0: x_dst, 1: x_src, 2: edge_attr
    int row = ((it & 7) << 3) + w;
    float2 v = {0.f, 0.f};
    if (e0 + row < E) {
      const float* sp;
      if (type == 0)      sp = node_x + (size_t)sDst[row] * FD;
      else if (type == 1) sp = node_x + (size_t)sSrc[row] * FD;
      else                sp = edge_attr + (size_t)(e0 + row) * FD;
      v = *(const float2*)(sp + lane * 2);
    }
    *(unsigned int*)&sA[row * 392 + type * 128 + lane * 2] = pack2(v.x, v.y);
  }
  __syncthreads();

  const float b0v = b0p[col], b1v = b1p[col], b2v = b2p[col];

  f32x4 acc[4];
#pragma unroll
  for (int m = 0; m < 4; ++m) acc[m] = (f32x4){0.f, 0.f, 0.f, 0.f};

  // ---- layer 0: K=384, B streamed (each frag loaded once per block) ----
  mfma_gB<12>(wp, sA, 392, acc, w, lane, g16, ln);
  store_tile<true>(sC, 136, acc, b0v, col, g16);
  __syncthreads();

  // ---- layer 1: K=128, B in registers ----
#pragma unroll
  for (int m = 0; m < 4; ++m) acc[m] = (f32x4){0.f, 0.f, 0.f, 0.f};
  mfma_rB<4>(B1r, sC, 136, acc, g16, ln);
  store_tile<true>(sA, 392, acc, b1v, col, g16);   // C1 -> sA cols 0..127
  __syncthreads();

  // ---- layer 2: K=128, B in registers ----
#pragma unroll
  for (int m = 0; m < 4; ++m) acc[m] = (f32x4){0.f, 0.f, 0.f, 0.f};
  mfma_rB<4>(B2r, sA, 392, acc, g16, ln);
  store_tile<false>(sC, 136, acc, b2v, col, g16);  // h2 -> sC
  __syncthreads();

  // ---- fused LN stats + epilogue, row-wise (8 threads per row) ----
  {
    int row = t >> 3, j = t & 7;
    bf16x8 v0 = *(const bf16x8*)&sC[row * 136 + j * 16];
    bf16x8 v1 = *(const bf16x8*)&sC[row * 136 + j * 16 + 8];
    float s1 = 0.f, s2 = 0.f;
#pragma unroll
    for (int q = 0; q < 8; ++q) {
      float a = (float)v0[q], b = (float)v1[q];
      s1 += a + b; s2 += a * a + b * b;
    }
#pragma unroll
    for (int m = 1; m < 8; m <<= 1) {
      s1 += __shfl_xor(s1, m, 64);
      s2 += __shfl_xor(s2, m, 64);
    }
    float mean = s1 * (1.f / 128.f);
    float var  = s2 * (1.f / 128.f) - mean * mean;
    float rstd = rsqrtf(fmaxf(var, 0.f) + 1e-5f);

    int e = e0 + row;
    if (e < E) {
      bf16x8 ea0 = *(const bf16x8*)&sA[row * 392 + 256 + j * 16];
      bf16x8 ea1 = *(const bf16x8*)&sA[row * 392 + 256 + j * 16 + 8];
      float val[16];
#pragma unroll
      for (int q = 0; q < 8; ++q) {
        val[q]     = ((float)v0[q] - mean) * rstd * sG[j * 16 + q]     + sB[j * 16 + q]     + (float)ea0[q];
        val[8 + q] = ((float)v1[q] - mean) * rstd * sG[j * 16 + 8 + q] + sB[j * 16 + 8 + q] + (float)ea1[q];
      }
      if (use_sort) {
        uint4* dst = (uint4*)(msg + (size_t)e * FD + j * 16);
        dst[0] = pack8(val);
        dst[1] = pack8(val + 8);
      } else {
        float* ap = agg + (size_t)sDst[row] * FD + j * 16;
#pragma unroll
        for (int q = 0; q < 16; ++q) atomicAdd(ap + q, val[q]);
      }
    }
  }
}

// Node kernel: 64 nodes/block; concat2=[node_x | agg] -> MLP(256->128->128->128)
// -> LN -> + node_x. agg gathered by walking the dst linked list (f32 sum of bf16
// msg rows), or read from f32 agg in fallback mode.
__global__ __launch_bounds__(512, 4)
void in_node_kernel(const float* __restrict__ node_x,
                    const unsigned short* __restrict__ msg, const int* __restrict__ head,
                    const int* __restrict__ nxt, const float* __restrict__ agg,
                    const unsigned short* __restrict__ wp,
                    const float* __restrict__ b0p, const float* __restrict__ b1p,
                    const float* __restrict__ b2p, const float* __restrict__ gp,
                    const float* __restrict__ bep, float* __restrict__ out,
                    int use_sort, int N) {
  __shared__ unsigned short sA[64 * 264];   // concat2 tile bf16, stride 264
  __shared__ unsigned short sC[64 * 136];
  __shared__ float sG[128], sB[128];

  const int t = threadIdx.x;
  const int r0 = blockIdx.x * 64;
  const int lane = t & 63, w = t >> 6;
  const int ln = lane & 15, g16 = lane >> 4;
  const int col = w * 16 + ln;

  bf16x8 B1r[4], B2r[4];
#pragma unroll
  for (int ks = 0; ks < 4; ++ks)
    B1r[ks] = *(const bf16x8*)(wp + 114688 + (size_t)((w * 4 + ks) * 64 + lane) * 8);
#pragma unroll
  for (int ks = 0; ks < 4; ++ks)
    B2r[ks] = *(const bf16x8*)(wp + 131072 + (size_t)((w * 4 + ks) * 64 + lane) * 8);

  if (t < 128)      sG[t] = gp[t];
  else if (t < 256) sB[t - 128] = bep[t - 128];

  // stage node_x cols 0..127: 64 wave-uniform segments, float2/lane
#pragma unroll
  for (int it = 0; it < 8; ++it) {
    int row = (it << 3) + w;
    int r = r0 + row;
    float2 v = {0.f, 0.f};
    if (r < N) v = *(const float2*)(node_x + (size_t)r * FD + lane * 2);
    *(unsigned int*)&sA[row * 264 + lane * 2] = pack2(v.x, v.y);
  }

  // stage agg cols 128..255: 8 threads per node, 16 cols each
  {
    int row = t >> 3, j = t & 7;
    int node = r0 + row;
    float a[16];
#pragma unroll
    for (int q = 0; q < 16; ++q) a[q] = 0.f;
    if (node < N) {
      if (use_sort) {
        int e = head[node];
        while (e >= 0) {
          int ne = nxt[e];
          bf16x8 m0 = *(const bf16x8*)(msg + (size_t)e * FD + j * 16);
          bf16x8 m1 = *(const bf16x8*)(msg + (size_t)e * FD + j * 16 + 8);
#pragma unroll
          for (int q = 0; q < 8; ++q) { a[q] += (float)m0[q]; a[8 + q] += (float)m1[q]; }
          e = ne;
        }
      } else {
        const float* ap = agg + (size_t)node * FD + j * 16;
#pragma unroll
        for (int q4 = 0; q4 < 4; ++q4) {
          f32x4 u = *(const f32x4*)(ap + q4 * 4);
#pragma unroll
          for (int q = 0; q < 4; ++q) a[q4 * 4 + q] = u[q];
        }
      }
    }
    uint4* dst = (uint4*)&sA[row * 264 + 128 + j * 16];
    dst[0] = pack8(a);
    dst[1] = pack8(a + 8);
  }
  __syncthreads();

  const float b0v = b0p[col], b1v = b1p[col], b2v = b2p[col];

  f32x4 acc[4];
#pragma unroll
  for (int m = 0; m < 4; ++m) acc[m] = (f32x4){0.f, 0.f, 0.f, 0.f};

  mfma_gB<8>(wp + 81920, sA, 264, acc, w, lane, g16, ln);
  store_tile<true>(sC, 136, acc, b0v, col, g16);
  __syncthreads();

#pragma unroll
  for (int m = 0; m < 4; ++m) acc[m] = (f32x4){0.f, 0.f, 0.f, 0.f};
  mfma_rB<4>(B1r, sC, 136, acc, g16, ln);
  store_tile<true>(sA, 264, acc, b1v, col, g16);   // C1 -> sA cols 0..127
  __syncthreads();

#pragma unroll
  for (int m = 0; m < 4; ++m) acc[m] = (f32x4){0.f, 0.f, 0.f, 0.f};
  mfma_rB<4>(B2r, sA, 264, acc, g16, ln);
  store_tile<false>(sC, 136, acc, b2v, col, g16);  // h2 -> sC
  __syncthreads();

  // ---- fused LN stats + residual + store, row-wise ----
  {
    int row = t >> 3, j = t & 7;
    bf16x8 v0 = *(const bf16x8*)&sC[row * 136 + j * 16];
    bf16x8 v1 = *(const bf16x8*)&sC[row * 136 + j * 16 + 8];
    float s1 = 0.f, s2 = 0.f;
#pragma unroll
    for (int q = 0; q < 8; ++q) {
      float a = (float)v0[q], b = (float)v1[q];
      s1 += a + b; s2 += a * a + b * b;
    }
#pragma unroll
    for (int m = 1; m < 8; m <<= 1) {
      s1 += __shfl_xor(s1, m, 64);
      s2 += __shfl_xor(s2, m, 64);
    }
    float mean = s1 * (1.f / 128.f);
    float var  = s2 * (1.f / 128.f) - mean * mean;
    float rstd = rsqrtf(fmaxf(var, 0.f) + 1e-5f);

    int node = r0 + row;
    if (node < N) {
      float o[16];
#pragma unroll
      for (int q = 0; q < 8; ++q) {
        o[q]     = ((float)v0[q] - mean) * rstd * sG[j * 16 + q]     + sB[j * 16 + q];
        o[8 + q] = ((float)v1[q] - mean) * rstd * sG[j * 16 + 8 + q] + sB[j * 16 + 8 + q];
      }
      const float* xr = node_x + (size_t)node * FD + j * 16;
      float* orow = out + (size_t)node * FD + j * 16;
#pragma unroll
      for (int q4 = 0; q4 < 4; ++q4) {
        f32x4 x = *(const f32x4*)(xr + q4 * 4);
        f32x4 wv;
#pragma unroll
        for (int q = 0; q < 4; ++q) wv[q] = o[q4 * 4 + q] + x[q];
        *(f32x4*)(orow + q4 * 4) = wv;
      }
    }
  }
}

extern "C" void kernel_launch(void* const* d_in, const int* in_sizes, int n_in,
                              void* d_out, int out_size, void* d_ws, size_t ws_size,
                              hipStream_t stream) {
  const float* node_x    = (const float*)d_in[0];
  const float* edge_attr = (const float*)d_in[1];
  const int*   eidx      = (const int*)d_in[2];
  const int N = in_sizes[0] / FD;
  const int E = in_sizes[1] / FD;

  char* ws = (char*)d_ws;
  unsigned short* wp = (unsigned short*)ws;                 // 294,912 B
  const size_t wpB = 294912;
  const size_t headOff = wpB;
  const size_t nextOff = headOff + (((size_t)N * 4 + 255) & ~(size_t)255);
  const size_t msgOff  = nextOff + (((size_t)E * 4 + 255) & ~(size_t)255);
  const size_t need    = msgOff + (size_t)E * FD * 2;

  int use_sort = (ws_size >= need) ? 1 : 0;
  int* head = nullptr; int* nxt = nullptr;
  unsigned short* msg = nullptr; float* agg = nullptr;

  if (use_sort) {
    head = (int*)(ws + headOff);
    nxt  = (int*)(ws + nextOff);
    msg  = (unsigned short*)(ws + msgOff);
    (void)hipMemsetAsync(head, 0xFF, (size_t)N * 4, stream);   // head = -1
  } else {
    agg = (float*)(ws + wpB);
    (void)hipMemsetAsync(agg, 0, (size_t)N * FD * sizeof(float), stream);
  }

  pack_weights<<<576, 256, 0, stream>>>(
      (const float*)d_in[3], (const float*)d_in[5], (const float*)d_in[7],
      (const float*)d_in[11], (const float*)d_in[13], (const float*)d_in[15], wp);
  in_edge_kernel<<<(E + 63) / 64, 512, 0, stream>>>(
      node_x, edge_attr, eidx, wp,
      (const float*)d_in[4], (const float*)d_in[6], (const float*)d_in[8],
      (const float*)d_in[9], (const float*)d_in[10],
      msg, head, nxt, agg, use_sort, E);
  in_node_kernel<<<(N + 63) / 64, 512, 0, stream>>>(
      node_x, msg, head, nxt, agg, wp,
      (const float*)d_in[12], (const float*)d_in[14], (const float*)d_in[16],
      (const float*)d_in[17], (const float*)d_in[18], (float*)d_out, use_sort, N);
}

// Round 6
// 278.076 us; speedup vs baseline: 2.0353x; 1.1598x over previous
//
#include <hip/hip_runtime.h>

typedef __attribute__((ext_vector_type(4))) float f32x4;
typedef __attribute__((ext_vector_type(8))) __bf16 bf16x8;

constexpr int FD = 128;   // feature dim D = H = 128

__device__ __forceinline__ uint4 pack8(const float* v) {
  union { __bf16 h[8]; uint4 u; } cv;
#pragma unroll
  for (int q = 0; q < 8; ++q) cv.h[q] = (__bf16)v[q];
  return cv.u;
}
__device__ __forceinline__ unsigned int pack2(float a, float b) {
  union { __bf16 h[2]; unsigned int u; } cv;
  cv.h[0] = (__bf16)a; cv.h[1] = (__bf16)b;
  return cv.u;
}

// node_x f32 -> bf16 table (halves random-gather bytes in the edge kernel)
__global__ void cvt_bf16(const float* __restrict__ x, unsigned short* __restrict__ o, int n8) {
  int i = blockIdx.x * 256 + threadIdx.x;
  if (i >= n8) return;
  const float* p = x + (size_t)i * 8;
  float v[8];
#pragma unroll
  for (int q = 0; q < 8; ++q) v[q] = p[q];
  *(uint4*)(o + (size_t)i * 8) = pack8(v);
}

// Pack a (K,128) f32 weight matrix into 16x16x32 MFMA B-fragment order, bf16:
// dst[((nt*KS + ks)*64 + lane)*8 + e] = W[k][n]
//   nt = n>>4, ks = k>>5, lane = ((k>>3)&3)*16 + (n&15), e = k&7
__global__ void pack_weights(const float* __restrict__ mw0, const float* __restrict__ mw1,
                             const float* __restrict__ mw2, const float* __restrict__ uw0,
                             const float* __restrict__ uw1, const float* __restrict__ uw2,
                             unsigned short* __restrict__ wp) {
  int tid = blockIdx.x * 256 + threadIdx.x;   // 576*256 == 147456 exactly
  const float* src; int base, K;
  if      (tid < 49152)  { src = mw0; base = 0;      K = 384; }
  else if (tid < 65536)  { src = mw1; base = 49152;  K = 128; }
  else if (tid < 81920)  { src = mw2; base = 65536;  K = 128; }
  else if (tid < 114688) { src = uw0; base = 81920;  K = 256; }
  else if (tid < 131072) { src = uw1; base = 114688; K = 128; }
  else                   { src = uw2; base = 131072; K = 128; }
  int i = tid - base;
  int k = i >> 7, n = i & 127;
  int KS = K >> 5;
  int dst = base + (((n >> 4) * KS + (k >> 5)) * 64 + ((k >> 3) & 3) * 16 + (n & 15)) * 8 + (k & 7);
  union { __bf16 h; unsigned short s; } cv; cv.h = (__bf16)src[i];
  wp[dst] = cv.s;
}

// Layer with B streamed from global (L2-resident; each fragment loaded by exactly
// ONE wave per block). Wave = 64 rows x 16 cols: 4 m-frags share each b-frag.
template<int KSTEPS>
__device__ __forceinline__ void mfma_gB(const unsigned short* __restrict__ wsrc,
                                        const unsigned short* sAsrc, int strideA,
                                        f32x4* acc, int w, int lane, int g16, int ln) {
#pragma unroll
  for (int ks = 0; ks < KSTEPS; ++ks) {
    bf16x8 b = *(const bf16x8*)(wsrc + (size_t)((w * KSTEPS + ks) * 64 + lane) * 8);
#pragma unroll
    for (int m = 0; m < 4; ++m) {
      bf16x8 a = *(const bf16x8*)&sAsrc[(m * 16 + ln) * strideA + ks * 32 + g16 * 8];
      acc[m] = __builtin_amdgcn_mfma_f32_16x16x32_bf16(a, b, acc[m], 0, 0, 0);
    }
  }
}

// Layer with B already in registers (zero global loads).
template<int KSTEPS>
__device__ __forceinline__ void mfma_rB(const bf16x8* B,
                                        const unsigned short* sAsrc, int strideA,
                                        f32x4* acc, int g16, int ln) {
#pragma unroll
  for (int ks = 0; ks < KSTEPS; ++ks) {
#pragma unroll
    for (int m = 0; m < 4; ++m) {
      bf16x8 a = *(const bf16x8*)&sAsrc[(m * 16 + ln) * strideA + ks * 32 + g16 * 8];
      acc[m] = __builtin_amdgcn_mfma_f32_16x16x32_bf16(a, B[ks], acc[m], 0, 0, 0);
    }
  }
}

// Store per-wave 64x16 tile (+bias, optional relu) as bf16 into [64][stride] LDS tile.
template<bool RELU>
__device__ __forceinline__ void store_tile(unsigned short* sDst, int stride,
                                           const f32x4* acc, float bias, int col, int g16) {
#pragma unroll
  for (int m = 0; m < 4; ++m)
#pragma unroll
    for (int ri = 0; ri < 4; ++ri) {
      float v = acc[m][ri] + bias;
      if (RELU) v = fmaxf(v, 0.f);
      union { __bf16 h; unsigned short s; } cv; cv.h = (__bf16)v;
      sDst[(m * 16 + g16 * 4 + ri) * stride + col] = cv.s;
    }
}

// Edge kernel: 64 edges/block, 512 threads = 8 waves, each wave owns cols w*16..+15.
// Single sA buffer, activations ping-pong inside it: C0->cols0-127, C1->cols128-255,
// h2->cols0-127; edge_attr stays in cols 256-383. LDS 51.7KB -> 3 blocks/CU.
__global__ __launch_bounds__(512, 6)
void in_edge_kernel(const float* __restrict__ node_x, const unsigned short* __restrict__ nxbf,
                    const float* __restrict__ edge_attr,
                    const int* __restrict__ eidx, const unsigned short* __restrict__ wp,
                    const float* __restrict__ b0p, const float* __restrict__ b1p,
                    const float* __restrict__ b2p, const float* __restrict__ gp,
                    const float* __restrict__ bep,
                    unsigned short* __restrict__ msg, int* __restrict__ head,
                    int* __restrict__ nxt, float* __restrict__ agg,
                    int use_sort, int E) {
  __shared__ unsigned short sA[64 * 392];
  __shared__ int sSrc[64], sDst[64];
  __shared__ float sG[128], sB[128];

  const int t = threadIdx.x;
  const int e0 = blockIdx.x * 64;
  const int lane = t & 63, w = t >> 6;
  const int ln = lane & 15, g16 = lane >> 4;
  const int col = w * 16 + ln;

  // preload layer-1/2 B fragments into registers (overlaps index/param staging)
  bf16x8 B1r[4], B2r[4];
#pragma unroll
  for (int ks = 0; ks < 4; ++ks)
    B1r[ks] = *(const bf16x8*)(wp + 49152 + (size_t)((w * 4 + ks) * 64 + lane) * 8);
#pragma unroll
  for (int ks = 0; ks < 4; ++ks)
    B2r[ks] = *(const bf16x8*)(wp + 65536 + (size_t)((w * 4 + ks) * 64 + lane) * 8);

  if (t < 64) {
    sSrc[t] = (e0 + t < E) ? eidx[e0 + t] : 0;
  } else if (t < 128) {
    int r = t - 64;
    int e = e0 + r;
    int d = (e < E) ? eidx[E + e] : 0;
    sDst[r] = d;
    if (use_sort && e < E) nxt[e] = atomicExch(&head[d], e);   // linked-list build
  } else if (t < 256) {
    sG[t - 128] = gp[t - 128];
  } else if (t < 384) {
    sB[t - 256] = bep[t - 256];
  }
  __syncthreads();

  // ---- stage concat tile ----
  if (nxbf) {
    // bf16 node rows: 16B/lane, 16 lanes per row
#pragma unroll
    for (int it = 0; it < 2; ++it) {
      int f = t + it * 512;
      int row = f >> 4, j = f & 15;
      uint4 v = {0, 0, 0, 0}, u = {0, 0, 0, 0};
      if (e0 + row < E) {
        v = *(const uint4*)(nxbf + (size_t)sDst[row] * FD + j * 8);
        u = *(const uint4*)(nxbf + (size_t)sSrc[row] * FD + j * 8);
      }
      *(uint4*)&sA[row * 392 + j * 8] = v;
      *(uint4*)&sA[row * 392 + 128 + j * 8] = u;
    }
  } else {
#pragma unroll
    for (int it = 0; it < 16; ++it) {
      const int type = it >> 3;
      int row = ((it & 7) << 3) + w;
      float2 v = {0.f, 0.f};
      if (e0 + row < E) {
        const float* sp = (type == 0) ? node_x + (size_t)sDst[row] * FD
                                      : node_x + (size_t)sSrc[row] * FD;
        v = *(const float2*)(sp + lane * 2);
      }
      *(unsigned int*)&sA[row * 392 + type * 128 + lane * 2] = pack2(v.x, v.y);
    }
  }
#pragma unroll
  for (int it = 0; it < 8; ++it) {
    int row = it * 8 + w;
    float2 v = {0.f, 0.f};
    if (e0 + row < E) v = *(const float2*)(edge_attr + (size_t)(e0 + row) * FD + lane * 2);
    *(unsigned int*)&sA[row * 392 + 256 + lane * 2] = pack2(v.x, v.y);
  }
  __syncthreads();

  const float b0v = b0p[col], b1v = b1p[col], b2v = b2p[col];

  f32x4 acc[4];
#pragma unroll
  for (int m = 0; m < 4; ++m) acc[m] = (f32x4){0.f, 0.f, 0.f, 0.f};

  // ---- layer 0: K=384, B streamed ----
  mfma_gB<12>(wp, sA, 392, acc, w, lane, g16, ln);
  __syncthreads();                                  // all L0 reads done
  store_tile<true>(sA, 392, acc, b0v, col, g16);    // C0 -> cols 0..127
  __syncthreads();

  // ---- layer 1 ----
#pragma unroll
  for (int m = 0; m < 4; ++m) acc[m] = (f32x4){0.f, 0.f, 0.f, 0.f};
  mfma_rB<4>(B1r, sA, 392, acc, g16, ln);
  store_tile<true>(sA + 128, 392, acc, b1v, col, g16);  // C1 -> cols 128..255 (x_src dead)
  __syncthreads();                                  // C1 visible + L1 reads done

  // ---- layer 2 ----
#pragma unroll
  for (int m = 0; m < 4; ++m) acc[m] = (f32x4){0.f, 0.f, 0.f, 0.f};
  mfma_rB<4>(B2r, sA + 128, 392, acc, g16, ln);
  store_tile<false>(sA, 392, acc, b2v, col, g16);   // h2 -> cols 0..127 (C0 dead)
  __syncthreads();

  // ---- fused LN stats + epilogue, row-wise (8 threads per row) ----
  {
    int row = t >> 3, j = t & 7;
    bf16x8 v0 = *(const bf16x8*)&sA[row * 392 + j * 16];
    bf16x8 v1 = *(const bf16x8*)&sA[row * 392 + j * 16 + 8];
    float s1 = 0.f, s2 = 0.f;
#pragma unroll
    for (int q = 0; q < 8; ++q) {
      float a = (float)v0[q], b = (float)v1[q];
      s1 += a + b; s2 += a * a + b * b;
    }
#pragma unroll
    for (int m = 1; m < 8; m <<= 1) {
      s1 += __shfl_xor(s1, m, 64);
      s2 += __shfl_xor(s2, m, 64);
    }
    float mean = s1 * (1.f / 128.f);
    float var  = s2 * (1.f / 128.f) - mean * mean;
    float rstd = rsqrtf(fmaxf(var, 0.f) + 1e-5f);

    int e = e0 + row;
    if (e < E) {
      bf16x8 ea0 = *(const bf16x8*)&sA[row * 392 + 256 + j * 16];
      bf16x8 ea1 = *(const bf16x8*)&sA[row * 392 + 256 + j * 16 + 8];
      float val[16];
#pragma unroll
      for (int q = 0; q < 8; ++q) {
        val[q]     = ((float)v0[q] - mean) * rstd * sG[j * 16 + q]     + sB[j * 16 + q]     + (float)ea0[q];
        val[8 + q] = ((float)v1[q] - mean) * rstd * sG[j * 16 + 8 + q] + sB[j * 16 + 8 + q] + (float)ea1[q];
      }
      if (use_sort) {
        uint4* dst = (uint4*)(msg + (size_t)e * FD + j * 16);
        dst[0] = pack8(val);
        dst[1] = pack8(val + 8);
      } else {
        float* ap = agg + (size_t)sDst[row] * FD + j * 16;
#pragma unroll
        for (int q = 0; q < 16; ++q) atomicAdd(ap + q, val[q]);
      }
    }
  }
}

// Node kernel: 64 nodes/block; concat2=[node_x | agg] -> MLP(256->128->128->128)
// -> LN -> + node_x. Single sA buffer (34.8KB -> 4 blocks/CU).
__global__ __launch_bounds__(512, 8)
void in_node_kernel(const float* __restrict__ node_x, const unsigned short* __restrict__ nxbf,
                    const unsigned short* __restrict__ msg, const int* __restrict__ head,
                    const int* __restrict__ nxt, const float* __restrict__ agg,
                    const unsigned short* __restrict__ wp,
                    const float* __restrict__ b0p, const float* __restrict__ b1p,
                    const float* __restrict__ b2p, const float* __restrict__ gp,
                    const float* __restrict__ bep, float* __restrict__ out,
                    int use_sort, int N) {
  __shared__ unsigned short sA[64 * 264];
  __shared__ float sG[128], sB[128];

  const int t = threadIdx.x;
  const int r0 = blockIdx.x * 64;
  const int lane = t & 63, w = t >> 6;
  const int ln = lane & 15, g16 = lane >> 4;
  const int col = w * 16 + ln;

  bf16x8 B1r[4], B2r[4];
#pragma unroll
  for (int ks = 0; ks < 4; ++ks)
    B1r[ks] = *(const bf16x8*)(wp + 114688 + (size_t)((w * 4 + ks) * 64 + lane) * 8);
#pragma unroll
  for (int ks = 0; ks < 4; ++ks)
    B2r[ks] = *(const bf16x8*)(wp + 131072 + (size_t)((w * 4 + ks) * 64 + lane) * 8);

  if (t < 128)      sG[t] = gp[t];
  else if (t < 256) sB[t - 128] = bep[t - 128];

  // stage node_x cols 0..127
  if (nxbf) {
#pragma unroll
    for (int it = 0; it < 2; ++it) {
      int f = t + it * 512;
      int row = f >> 4, j = f & 15;
      int r = r0 + row;
      uint4 v = {0, 0, 0, 0};
      if (r < N) v = *(const uint4*)(nxbf + (size_t)r * FD + j * 8);
      *(uint4*)&sA[row * 264 + j * 8] = v;
    }
  } else {
#pragma unroll
    for (int it = 0; it < 8; ++it) {
      int row = (it << 3) + w;
      int r = r0 + row;
      float2 v = {0.f, 0.f};
      if (r < N) v = *(const float2*)(node_x + (size_t)r * FD + lane * 2);
      *(unsigned int*)&sA[row * 264 + lane * 2] = pack2(v.x, v.y);
    }
  }

  // stage agg cols 128..255: 8 threads per node, 16 cols each
  {
    int row = t >> 3, j = t & 7;
    int node = r0 + row;
    float a[16];
#pragma unroll
    for (int q = 0; q < 16; ++q) a[q] = 0.f;
    if (node < N) {
      if (use_sort) {
        int e = head[node];
        while (e >= 0) {
          int ne = nxt[e];
          bf16x8 m0 = *(const bf16x8*)(msg + (size_t)e * FD + j * 16);
          bf16x8 m1 = *(const bf16x8*)(msg + (size_t)e * FD + j * 16 + 8);
#pragma unroll
          for (int q = 0; q < 8; ++q) { a[q] += (float)m0[q]; a[8 + q] += (float)m1[q]; }
          e = ne;
        }
      } else {
        const float* ap = agg + (size_t)node * FD + j * 16;
#pragma unroll
        for (int q4 = 0; q4 < 4; ++q4) {
          f32x4 u = *(const f32x4*)(ap + q4 * 4);
#pragma unroll
          for (int q = 0; q < 4; ++q) a[q4 * 4 + q] = u[q];
        }
      }
    }
    uint4* dst = (uint4*)&sA[row * 264 + 128 + j * 16];
    dst[0] = pack8(a);
    dst[1] = pack8(a + 8);
  }
  __syncthreads();

  const float b0v = b0p[col], b1v = b1p[col], b2v = b2p[col];

  f32x4 acc[4];
#pragma unroll
  for (int m = 0; m < 4; ++m) acc[m] = (f32x4){0.f, 0.f, 0.f, 0.f};

  mfma_gB<8>(wp + 81920, sA, 264, acc, w, lane, g16, ln);
  __syncthreads();                                  // all L0 reads done
  store_tile<true>(sA, 264, acc, b0v, col, g16);    // C0 -> cols 0..127
  __syncthreads();

#pragma unroll
  for (int m = 0; m < 4; ++m) acc[m] = (f32x4){0.f, 0.f, 0.f, 0.f};
  mfma_rB<4>(B1r, sA, 264, acc, g16, ln);
  store_tile<true>(sA + 128, 264, acc, b1v, col, g16);  // C1 -> cols 128..255
  __syncthreads();

#pragma unroll
  for (int m = 0; m < 4; ++m) acc[m] = (f32x4){0.f, 0.f, 0.f, 0.f};
  mfma_rB<4>(B2r, sA + 128, 264, acc, g16, ln);
  store_tile<false>(sA, 264, acc, b2v, col, g16);   // h2 -> cols 0..127
  __syncthreads();

  // ---- fused LN stats + residual + store, row-wise ----
  {
    int row = t >> 3, j = t & 7;
    bf16x8 v0 = *(const bf16x8*)&sA[row * 264 + j * 16];
    bf16x8 v1 = *(const bf16x8*)&sA[row * 264 + j * 16 + 8];
    float s1 = 0.f, s2 = 0.f;
#pragma unroll
    for (int q = 0; q < 8; ++q) {
      float a = (float)v0[q], b = (float)v1[q];
      s1 += a + b; s2 += a * a + b * b;
    }
#pragma unroll
    for (int m = 1; m < 8; m <<= 1) {
      s1 += __shfl_xor(s1, m, 64);
      s2 += __shfl_xor(s2, m, 64);
    }
    float mean = s1 * (1.f / 128.f);
    float var  = s2 * (1.f / 128.f) - mean * mean;
    float rstd = rsqrtf(fmaxf(var, 0.f) + 1e-5f);

    int node = r0 + row;
    if (node < N) {
      float o[16];
#pragma unroll
      for (int q = 0; q < 8; ++q) {
        o[q]     = ((float)v0[q] - mean) * rstd * sG[j * 16 + q]     + sB[j * 16 + q];
        o[8 + q] = ((float)v1[q] - mean) * rstd * sG[j * 16 + 8 + q] + sB[j * 16 + 8 + q];
      }
      const float* xr = node_x + (size_t)node * FD + j * 16;
      float* orow = out + (size_t)node * FD + j * 16;
#pragma unroll
      for (int q4 = 0; q4 < 4; ++q4) {
        f32x4 x = *(const f32x4*)(xr + q4 * 4);
        f32x4 wv;
#pragma unroll
        for (int q = 0; q < 4; ++q) wv[q] = o[q4 * 4 + q] + x[q];
        *(f32x4*)(orow + q4 * 4) = wv;
      }
    }
  }
}

extern "C" void kernel_launch(void* const* d_in, const int* in_sizes, int n_in,
                              void* d_out, int out_size, void* d_ws, size_t ws_size,
                              hipStream_t stream) {
  const float* node_x    = (const float*)d_in[0];
  const float* edge_attr = (const float*)d_in[1];
  const int*   eidx      = (const int*)d_in[2];
  const int N = in_sizes[0] / FD;
  const int E = in_sizes[1] / FD;

  char* ws = (char*)d_ws;
  auto aln = [](size_t x) { return (x + 255) & ~(size_t)255; };
  const size_t wpB   = aln(294912);
  const size_t nxbfB = aln((size_t)N * FD * 2);
  const size_t headB = aln((size_t)N * 4);
  const size_t nxtB  = aln((size_t)E * 4);
  const size_t msgB  = (size_t)E * FD * 2;

  unsigned short* wp = (unsigned short*)ws;
  unsigned short* nxbf = nullptr;
  int* head = nullptr; int* nxt = nullptr;
  unsigned short* msg = nullptr; float* agg = nullptr;
  int use_sort = 0;

  if (ws_size >= wpB + nxbfB + headB + nxtB + msgB) {          // full: bf16 table + sort
    use_sort = 1;
    nxbf = (unsigned short*)(ws + wpB);
    head = (int*)(ws + wpB + nxbfB);
    nxt  = (int*)(ws + wpB + nxbfB + headB);
    msg  = (unsigned short*)(ws + wpB + nxbfB + headB + nxtB);
  } else if (ws_size >= wpB + headB + nxtB + msgB) {           // sort, no bf16 table
    use_sort = 1;
    head = (int*)(ws + wpB);
    nxt  = (int*)(ws + wpB + headB);
    msg  = (unsigned short*)(ws + wpB + headB + nxtB);
  } else {                                                     // atomic fallback
    agg = (float*)(ws + wpB);
  }

  if (use_sort) (void)hipMemsetAsync(head, 0xFF, (size_t)N * 4, stream);
  else          (void)hipMemsetAsync(agg, 0, (size_t)N * FD * sizeof(float), stream);

  pack_weights<<<576, 256, 0, stream>>>(
      (const float*)d_in[3], (const float*)d_in[5], (const float*)d_in[7],
      (const float*)d_in[11], (const float*)d_in[13], (const float*)d_in[15], wp);
  if (nxbf) cvt_bf16<<<(N * FD / 8 + 255) / 256, 256, 0, stream>>>(node_x, nxbf, N * FD / 8);
  in_edge_kernel<<<(E + 63) / 64, 512, 0, stream>>>(
      node_x, nxbf, edge_attr, eidx, wp,
      (const float*)d_in[4], (const float*)d_in[6], (const float*)d_in[8],
      (const float*)d_in[9], (const float*)d_in[10],
      msg, head, nxt, agg, use_sort, E);
  in_node_kernel<<<(N + 63) / 64, 512, 0, stream>>>(
      node_x, nxbf, msg, head, nxt, agg, wp,
      (const float*)d_in[12], (const float*)d_in[14], (const float*)d_in[16],
      (const float*)d_in[17], (const float*)d_in[18], (float*)d_out, use_sort, N);
}

// Round 7
// 239.444 us; speedup vs baseline: 2.3637x; 1.1613x over previous
//
#include <hip/hip_runtime.h>

typedef __attribute__((ext_vector_type(4))) float f32x4;
typedef __attribute__((ext_vector_type(8))) __bf16 bf16x8;

constexpr int FD = 128;   // feature dim D = H = 128

__device__ __forceinline__ uint4 pack8(const float* v) {
  union { __bf16 h[8]; uint4 u; } cv;
#pragma unroll
  for (int q = 0; q < 8; ++q) cv.h[q] = (__bf16)v[q];
  return cv.u;
}
__device__ __forceinline__ unsigned int pack2(float a, float b) {
  union { __bf16 h[2]; unsigned int u; } cv;
  cv.h[0] = (__bf16)a; cv.h[1] = (__bf16)b;
  return cv.u;
}

// node_x f32 -> bf16 table (halves random-gather bytes in the edge kernel)
__global__ void cvt_bf16(const float* __restrict__ x, unsigned short* __restrict__ o, int n8) {
  int i = blockIdx.x * 256 + threadIdx.x;
  if (i >= n8) return;
  const float* p = x + (size_t)i * 8;
  float v[8];
#pragma unroll
  for (int q = 0; q < 8; ++q) v[q] = p[q];
  *(uint4*)(o + (size_t)i * 8) = pack8(v);
}

// Pack a (K,128) f32 weight matrix into 16x16x32 MFMA B-fragment order, bf16:
// dst[((nt*KS + ks)*64 + lane)*8 + e] = W[k][n]
//   nt = n>>4, ks = k>>5, lane = ((k>>3)&3)*16 + (n&15), e = k&7
__global__ void pack_weights(const float* __restrict__ mw0, const float* __restrict__ mw1,
                             const float* __restrict__ mw2, const float* __restrict__ uw0,
                             const float* __restrict__ uw1, const float* __restrict__ uw2,
                             unsigned short* __restrict__ wp) {
  int tid = blockIdx.x * 256 + threadIdx.x;   // 576*256 == 147456 exactly
  const float* src; int base, K;
  if      (tid < 49152)  { src = mw0; base = 0;      K = 384; }
  else if (tid < 65536)  { src = mw1; base = 49152;  K = 128; }
  else if (tid < 81920)  { src = mw2; base = 65536;  K = 128; }
  else if (tid < 114688) { src = uw0; base = 81920;  K = 256; }
  else if (tid < 131072) { src = uw1; base = 114688; K = 128; }
  else                   { src = uw2; base = 131072; K = 128; }
  int i = tid - base;
  int k = i >> 7, n = i & 127;
  int KS = K >> 5;
  int dst = base + (((n >> 4) * KS + (k >> 5)) * 64 + ((k >> 3) & 3) * 16 + (n & 15)) * 8 + (k & 7);
  union { __bf16 h; unsigned short s; } cv; cv.h = (__bf16)src[i];
  wp[dst] = cv.s;
}

// Fragment-order LDS layout for MFMA operand tiles:
//   chunk(ks, m, lane) at shorts offset ((ks*4 + m)*64 + (lane&15)*4 + (lane>>4))*8
//   holding A[m*16 + (lane&15)][ks*32 + (lane>>4)*8 .. +8].
// MFMA reads are then 64 distinct consecutive 16B chunks -> zero bank conflicts.

// Store per-wave 64x16 output tile (+bias, opt relu) as bf16 into frag-order dest.
// sDst must be sBuf + base + stoff (stoff precomputed per thread).
template<bool RELU>
__device__ __forceinline__ void store_frag(unsigned short* sDst, const f32x4* acc, float bias) {
#pragma unroll
  for (int m = 0; m < 4; ++m)
#pragma unroll
    for (int ri = 0; ri < 4; ++ri) {
      float v = acc[m][ri] + bias;
      if (RELU) v = fmaxf(v, 0.f);
      union { __bf16 h; unsigned short s; } cv; cv.h = (__bf16)v;
      sDst[m * 512 + ri * 32] = cv.s;
    }
}

// Edge kernel: 64 edges/block, 512 threads = 8 waves, wave w owns cols w*16..+15.
// concat=[x_dst | x_src | edge_attr] (frag chunks 0..1023 | 1024..2047 | 2048..3071)
// -> MLP(384->128->128->128) -> LN -> +edge_attr -> msg[e] + linked list.
__global__ __launch_bounds__(512, 6)
void in_edge_kernel(const float* __restrict__ node_x, const unsigned short* __restrict__ nxbf,
                    const float* __restrict__ edge_attr,
                    const int* __restrict__ eidx, const unsigned short* __restrict__ wp,
                    const float* __restrict__ b0p, const float* __restrict__ b1p,
                    const float* __restrict__ b2p, const float* __restrict__ gp,
                    const float* __restrict__ bep,
                    unsigned short* __restrict__ msg, int* __restrict__ head,
                    int* __restrict__ nxt, float* __restrict__ agg,
                    int use_sort, int E) {
  __shared__ unsigned short sBuf[3072 * 8];   // 48KB frag-order buffer
  __shared__ int sSrc[64], sDst[64];
  __shared__ float sG[128], sB[128];

  const int t = threadIdx.x;
  const int e0 = blockIdx.x * 64;
  const int lane = t & 63, w = t >> 6;
  const int ln = lane & 15, g16 = lane >> 4;
  const int col = w * 16 + ln;
  const int rdoff = ln * 32 + g16 * 8;                       // frag read offset (shorts)
  const int stoff = (w >> 1) * 2048 + g16 * 128              // frag store offset (shorts)
                  + (((2 * w) + (ln >> 3)) & 3) * 8 + (ln & 7);

  // L0 B pipeline: 6-deep register rotation, initial loads issued before staging
  bf16x8 b0[6];
#pragma unroll
  for (int ks = 0; ks < 6; ++ks)
    b0[ks] = *(const bf16x8*)(wp + (size_t)((w * 12 + ks) * 64 + lane) * 8);
  bf16x8 B1r[4];
#pragma unroll
  for (int ks = 0; ks < 4; ++ks)
    B1r[ks] = *(const bf16x8*)(wp + 49152 + (size_t)((w * 4 + ks) * 64 + lane) * 8);

  if (t < 64) {
    sSrc[t] = (e0 + t < E) ? eidx[e0 + t] : 0;
  } else if (t < 128) {
    int r = t - 64;
    int e = e0 + r;
    int d = (e < E) ? eidx[E + e] : 0;
    sDst[r] = d;
    if (use_sort && e < E) nxt[e] = atomicExch(&head[d], e);   // linked-list build
  } else if (t < 256) {
    sG[t - 128] = gp[t - 128];
  } else if (t < 384) {
    sB[t - 256] = bep[t - 256];
  }
  __syncthreads();

  // ---- stage concat tile into frag order ----
  if (nxbf) {
#pragma unroll
    for (int it = 0; it < 2; ++it) {
      int f = t + it * 512;
      int row = f >> 4, j = f & 15;
      uint4 v = {0, 0, 0, 0}, u = {0, 0, 0, 0};
      if (e0 + row < E) {
        v = *(const uint4*)(nxbf + (size_t)sDst[row] * FD + j * 8);
        u = *(const uint4*)(nxbf + (size_t)sSrc[row] * FD + j * 8);
      }
      int c = (((j >> 2) * 4 + (row >> 4)) * 64 + (row & 15) * 4 + (j & 3)) * 8;
      *(uint4*)&sBuf[c] = v;                 // x_dst: ks 0..3
      *(uint4*)&sBuf[c + 8192] = u;          // x_src: ks 4..7 (+1024 chunks)
    }
  } else {
#pragma unroll
    for (int it = 0; it < 16; ++it) {
      const int type = it >> 3;
      int row = ((it & 7) << 3) + w;
      float2 v = {0.f, 0.f};
      if (e0 + row < E) {
        const float* sp = (type == 0) ? node_x + (size_t)sDst[row] * FD
                                      : node_x + (size_t)sSrc[row] * FD;
        v = *(const float2*)(sp + lane * 2);
      }
      int c = (((type * 4 + (lane >> 4)) * 4 + (row >> 4)) * 64
               + (row & 15) * 4 + ((lane >> 2) & 3)) * 8 + (lane & 3) * 2;
      *(unsigned int*)&sBuf[c] = pack2(v.x, v.y);
    }
  }
#pragma unroll
  for (int it = 0; it < 8; ++it) {           // edge_attr -> ks 8..11 (chunks 2048+)
    int row = it * 8 + w;
    float2 v = {0.f, 0.f};
    if (e0 + row < E) v = *(const float2*)(edge_attr + (size_t)(e0 + row) * FD + lane * 2);
    int c = 16384 + (((lane >> 4) * 4 + (row >> 4)) * 64
                     + (row & 15) * 4 + ((lane >> 2) & 3)) * 8 + (lane & 3) * 2;
    *(unsigned int*)&sBuf[c] = pack2(v.x, v.y);
  }
  __syncthreads();

  const float b0v = b0p[col], b1v = b1p[col], b2v = b2p[col];

  f32x4 acc[4];
#pragma unroll
  for (int m = 0; m < 4; ++m) acc[m] = (f32x4){0.f, 0.f, 0.f, 0.f};

  // ---- layer 0: K=384, pipelined B ----
#pragma unroll
  for (int ks = 0; ks < 12; ++ks) {
    bf16x8 bb = b0[ks % 6];
    if (ks + 6 < 12)
      b0[ks % 6] = *(const bf16x8*)(wp + (size_t)((w * 12 + ks + 6) * 64 + lane) * 8);
#pragma unroll
    for (int m = 0; m < 4; ++m) {
      bf16x8 a = *(const bf16x8*)&sBuf[(ks * 4 + m) * 512 + rdoff];
      acc[m] = __builtin_amdgcn_mfma_f32_16x16x32_bf16(a, bb, acc[m], 0, 0, 0);
    }
  }
  // issue B2 loads now (hidden under C0 store + barrier + L1)
  bf16x8 B2r[4];
#pragma unroll
  for (int ks = 0; ks < 4; ++ks)
    B2r[ks] = *(const bf16x8*)(wp + 65536 + (size_t)((w * 4 + ks) * 64 + lane) * 8);

  __syncthreads();                                  // all L0 A-reads done
  store_frag<true>(sBuf + stoff, acc, b0v);         // C0 -> chunks 0..1023
  __syncthreads();

  // ---- layer 1 ----
#pragma unroll
  for (int m = 0; m < 4; ++m) acc[m] = (f32x4){0.f, 0.f, 0.f, 0.f};
#pragma unroll
  for (int ks = 0; ks < 4; ++ks)
#pragma unroll
    for (int m = 0; m < 4; ++m) {
      bf16x8 a = *(const bf16x8*)&sBuf[(ks * 4 + m) * 512 + rdoff];
      acc[m] = __builtin_amdgcn_mfma_f32_16x16x32_bf16(a, B1r[ks], acc[m], 0, 0, 0);
    }
  store_frag<true>(sBuf + 8192 + stoff, acc, b1v);  // C1 -> chunks 1024..2047 (x_src dead)
  __syncthreads();

  // ---- layer 2 ----
#pragma unroll
  for (int m = 0; m < 4; ++m) acc[m] = (f32x4){0.f, 0.f, 0.f, 0.f};
#pragma unroll
  for (int ks = 0; ks < 4; ++ks)
#pragma unroll
    for (int m = 0; m < 4; ++m) {
      bf16x8 a = *(const bf16x8*)&sBuf[8192 + (ks * 4 + m) * 512 + rdoff];
      acc[m] = __builtin_amdgcn_mfma_f32_16x16x32_bf16(a, B2r[ks], acc[m], 0, 0, 0);
    }
  store_frag<false>(sBuf + stoff, acc, b2v);        // h2 -> chunks 0..1023 (C0 dead)
  __syncthreads();

  // ---- fused LN stats + epilogue, row-wise (8 threads per row) ----
  {
    int row = t >> 3, j = t & 7;
    int a0 = (((j >> 1) * 4 + (row >> 4)) * 64 + (row & 15) * 4 + 2 * (j & 1)) * 8;
    bf16x8 v0 = *(const bf16x8*)&sBuf[a0];
    bf16x8 v1 = *(const bf16x8*)&sBuf[a0 + 8];
    float s1 = 0.f, s2 = 0.f;
#pragma unroll
    for (int q = 0; q < 8; ++q) {
      float a = (float)v0[q], b = (float)v1[q];
      s1 += a + b; s2 += a * a + b * b;
    }
#pragma unroll
    for (int m = 1; m < 8; m <<= 1) {
      s1 += __shfl_xor(s1, m, 64);
      s2 += __shfl_xor(s2, m, 64);
    }
    float mean = s1 * (1.f / 128.f);
    float var  = s2 * (1.f / 128.f) - mean * mean;
    float rstd = rsqrtf(fmaxf(var, 0.f) + 1e-5f);

    int e = e0 + row;
    if (e < E) {
      bf16x8 ea0 = *(const bf16x8*)&sBuf[a0 + 16384];
      bf16x8 ea1 = *(const bf16x8*)&sBuf[a0 + 16384 + 8];
      float val[16];
#pragma unroll
      for (int q = 0; q < 8; ++q) {
        val[q]     = ((float)v0[q] - mean) * rstd * sG[j * 16 + q]     + sB[j * 16 + q]     + (float)ea0[q];
        val[8 + q] = ((float)v1[q] - mean) * rstd * sG[j * 16 + 8 + q] + sB[j * 16 + 8 + q] + (float)ea1[q];
      }
      if (use_sort) {
        uint4* dst = (uint4*)(msg + (size_t)e * FD + j * 16);
        dst[0] = pack8(val);
        dst[1] = pack8(val + 8);
      } else {
        float* ap = agg + (size_t)sDst[row] * FD + j * 16;
#pragma unroll
        for (int q = 0; q < 16; ++q) atomicAdd(ap + q, val[q]);
      }
    }
  }
}

// Node kernel: 64 nodes/block; concat2=[node_x | agg] (frag chunks 0..1023 | 1024..2047)
// -> MLP(256->128->128->128) -> LN -> + node_x.
__global__ __launch_bounds__(512, 8)
void in_node_kernel(const float* __restrict__ node_x, const unsigned short* __restrict__ nxbf,
                    const unsigned short* __restrict__ msg, const int* __restrict__ head,
                    const int* __restrict__ nxt, const float* __restrict__ agg,
                    const unsigned short* __restrict__ wp,
                    const float* __restrict__ b0p, const float* __restrict__ b1p,
                    const float* __restrict__ b2p, const float* __restrict__ gp,
                    const float* __restrict__ bep, float* __restrict__ out,
                    int use_sort, int N) {
  __shared__ unsigned short sBuf[2048 * 8];   // 32KB frag-order buffer
  __shared__ float sG[128], sB[128];

  const int t = threadIdx.x;
  const int r0 = blockIdx.x * 64;
  const int lane = t & 63, w = t >> 6;
  const int ln = lane & 15, g16 = lane >> 4;
  const int col = w * 16 + ln;
  const int rdoff = ln * 32 + g16 * 8;
  const int stoff = (w >> 1) * 2048 + g16 * 128
                  + (((2 * w) + (ln >> 3)) & 3) * 8 + (ln & 7);

  bf16x8 b0[4];
#pragma unroll
  for (int ks = 0; ks < 4; ++ks)
    b0[ks] = *(const bf16x8*)(wp + 81920 + (size_t)((w * 8 + ks) * 64 + lane) * 8);

  if (t < 128)      sG[t] = gp[t];
  else if (t < 256) sB[t - 128] = bep[t - 128];

  // stage node_x (ks 0..3) into frag order
  if (nxbf) {
#pragma unroll
    for (int it = 0; it < 2; ++it) {
      int f = t + it * 512;
      int row = f >> 4, j = f & 15;
      int r = r0 + row;
      uint4 v = {0, 0, 0, 0};
      if (r < N) v = *(const uint4*)(nxbf + (size_t)r * FD + j * 8);
      int c = (((j >> 2) * 4 + (row >> 4)) * 64 + (row & 15) * 4 + (j & 3)) * 8;
      *(uint4*)&sBuf[c] = v;
    }
  } else {
#pragma unroll
    for (int it = 0; it < 8; ++it) {
      int row = (it << 3) + w;
      int r = r0 + row;
      float2 v = {0.f, 0.f};
      if (r < N) v = *(const float2*)(node_x + (size_t)r * FD + lane * 2);
      int c = (((lane >> 4) * 4 + (row >> 4)) * 64
               + (row & 15) * 4 + ((lane >> 2) & 3)) * 8 + (lane & 3) * 2;
      *(unsigned int*)&sBuf[c] = pack2(v.x, v.y);
    }
  }

  // stage agg (ks 4..7): 8 threads per node, 16 cols each, linked-list walk
  {
    int row = t >> 3, j = t & 7;
    int node = r0 + row;
    float a[16];
#pragma unroll
    for (int q = 0; q < 16; ++q) a[q] = 0.f;
    if (node < N) {
      if (use_sort) {
        int e = head[node];
        while (e >= 0) {
          int ne = nxt[e];
          bf16x8 m0 = *(const bf16x8*)(msg + (size_t)e * FD + j * 16);
          bf16x8 m1 = *(const bf16x8*)(msg + (size_t)e * FD + j * 16 + 8);
#pragma unroll
          for (int q = 0; q < 8; ++q) { a[q] += (float)m0[q]; a[8 + q] += (float)m1[q]; }
          e = ne;
        }
      } else {
        const float* ap = agg + (size_t)node * FD + j * 16;
#pragma unroll
        for (int q4 = 0; q4 < 4; ++q4) {
          f32x4 u = *(const f32x4*)(ap + q4 * 4);
#pragma unroll
          for (int q = 0; q < 4; ++q) a[q4 * 4 + q] = u[q];
        }
      }
    }
    int c = 8192 + (((j >> 1) * 4 + (row >> 4)) * 64 + (row & 15) * 4 + 2 * (j & 1)) * 8;
    *(uint4*)&sBuf[c] = pack8(a);
    *(uint4*)&sBuf[c + 8] = pack8(a + 8);
  }
  __syncthreads();

  const float b0v = b0p[col], b1v = b1p[col], b2v = b2p[col];

  f32x4 acc[4];
#pragma unroll
  for (int m = 0; m < 4; ++m) acc[m] = (f32x4){0.f, 0.f, 0.f, 0.f};

  // ---- layer 0: K=256, pipelined B ----
#pragma unroll
  for (int ks = 0; ks < 8; ++ks) {
    bf16x8 bb = b0[ks % 4];
    if (ks + 4 < 8)
      b0[ks % 4] = *(const bf16x8*)(wp + 81920 + (size_t)((w * 8 + ks + 4) * 64 + lane) * 8);
#pragma unroll
    for (int m = 0; m < 4; ++m) {
      bf16x8 a = *(const bf16x8*)&sBuf[(ks * 4 + m) * 512 + rdoff];
      acc[m] = __builtin_amdgcn_mfma_f32_16x16x32_bf16(a, bb, acc[m], 0, 0, 0);
    }
  }
  bf16x8 B1r[4];
#pragma unroll
  for (int ks = 0; ks < 4; ++ks)
    B1r[ks] = *(const bf16x8*)(wp + 114688 + (size_t)((w * 4 + ks) * 64 + lane) * 8);

  __syncthreads();
  store_frag<true>(sBuf + stoff, acc, b0v);          // C0 -> chunks 0..1023
  __syncthreads();

#pragma unroll
  for (int m = 0; m < 4; ++m) acc[m] = (f32x4){0.f, 0.f, 0.f, 0.f};
#pragma unroll
  for (int ks = 0; ks < 4; ++ks)
#pragma unroll
    for (int m = 0; m < 4; ++m) {
      bf16x8 a = *(const bf16x8*)&sBuf[(ks * 4 + m) * 512 + rdoff];
      acc[m] = __builtin_amdgcn_mfma_f32_16x16x32_bf16(a, B1r[ks], acc[m], 0, 0, 0);
    }
  bf16x8 B2r[4];
#pragma unroll
  for (int ks = 0; ks < 4; ++ks)
    B2r[ks] = *(const bf16x8*)(wp + 131072 + (size_t)((w * 4 + ks) * 64 + lane) * 8);
  store_frag<true>(sBuf + 8192 + stoff, acc, b1v);   // C1 -> chunks 1024..2047
  __syncthreads();

#pragma unroll
  for (int m = 0; m < 4; ++m) acc[m] = (f32x4){0.f, 0.f, 0.f, 0.f};
#pragma unroll
  for (int ks = 0; ks < 4; ++ks)
#pragma unroll
    for (int m = 0; m < 4; ++m) {
      bf16x8 a = *(const bf16x8*)&sBuf[8192 + (ks * 4 + m) * 512 + rdoff];
      acc[m] = __builtin_amdgcn_mfma_f32_16x16x32_bf16(a, B2r[ks], acc[m], 0, 0, 0);
    }
  store_frag<false>(sBuf + stoff, acc, b2v);         // h2 -> chunks 0..1023
  __syncthreads();

  // ---- fused LN stats + residual + store, row-wise ----
  {
    int row = t >> 3, j = t & 7;
    int a0 = (((j >> 1) * 4 + (row >> 4)) * 64 + (row & 15) * 4 + 2 * (j & 1)) * 8;
    bf16x8 v0 = *(const bf16x8*)&sBuf[a0];
    bf16x8 v1 = *(const bf16x8*)&sBuf[a0 + 8];
    float s1 = 0.f, s2 = 0.f;
#pragma unroll
    for (int q = 0; q < 8; ++q) {
      float a = (float)v0[q], b = (float)v1[q];
      s1 += a + b; s2 += a * a + b * b;
    }
#pragma unroll
    for (int m = 1; m < 8; m <<= 1) {
      s1 += __shfl_xor(s1, m, 64);
      s2 += __shfl_xor(s2, m, 64);
    }
    float mean = s1 * (1.f / 128.f);
    float var  = s2 * (1.f / 128.f) - mean * mean;
    float rstd = rsqrtf(fmaxf(var, 0.f) + 1e-5f);

    int node = r0 + row;
    if (node < N) {
      float o[16];
#pragma unroll
      for (int q = 0; q < 8; ++q) {
        o[q]     = ((float)v0[q] - mean) * rstd * sG[j * 16 + q]     + sB[j * 16 + q];
        o[8 + q] = ((float)v1[q] - mean) * rstd * sG[j * 16 + 8 + q] + sB[j * 16 + 8 + q];
      }
      const float* xr = node_x + (size_t)node * FD + j * 16;
      float* orow = out + (size_t)node * FD + j * 16;
#pragma unroll
      for (int q4 = 0; q4 < 4; ++q4) {
        f32x4 x = *(const f32x4*)(xr + q4 * 4);
        f32x4 wv;
#pragma unroll
        for (int q = 0; q < 4; ++q) wv[q] = o[q4 * 4 + q] + x[q];
        *(f32x4*)(orow + q4 * 4) = wv;
      }
    }
  }
}

extern "C" void kernel_launch(void* const* d_in, const int* in_sizes, int n_in,
                              void* d_out, int out_size, void* d_ws, size_t ws_size,
                              hipStream_t stream) {
  const float* node_x    = (const float*)d_in[0];
  const float* edge_attr = (const float*)d_in[1];
  const int*   eidx      = (const int*)d_in[2];
  const int N = in_sizes[0] / FD;
  const int E = in_sizes[1] / FD;

  char* ws = (char*)d_ws;
  auto aln = [](size_t x) { return (x + 255) & ~(size_t)255; };
  const size_t wpB   = aln(294912);
  const size_t nxbfB = aln((size_t)N * FD * 2);
  const size_t headB = aln((size_t)N * 4);
  const size_t nxtB  = aln((size_t)E * 4);
  const size_t msgB  = (size_t)E * FD * 2;

  unsigned short* wp = (unsigned short*)ws;
  unsigned short* nxbf = nullptr;
  int* head = nullptr; int* nxt = nullptr;
  unsigned short* msg = nullptr; float* agg = nullptr;
  int use_sort = 0;

  if (ws_size >= wpB + nxbfB + headB + nxtB + msgB) {          // full: bf16 table + sort
    use_sort = 1;
    nxbf = (unsigned short*)(ws + wpB);
    head = (int*)(ws + wpB + nxbfB);
    nxt  = (int*)(ws + wpB + nxbfB + headB);
    msg  = (unsigned short*)(ws + wpB + nxbfB + headB + nxtB);
  } else if (ws_size >= wpB + headB + nxtB + msgB) {           // sort, no bf16 table
    use_sort = 1;
    head = (int*)(ws + wpB);
    nxt  = (int*)(ws + wpB + headB);
    msg  = (unsigned short*)(ws + wpB + headB + nxtB);
  } else {                                                     // atomic fallback
    agg = (float*)(ws + wpB);
  }

  if (use_sort) (void)hipMemsetAsync(head, 0xFF, (size_t)N * 4, stream);
  else          (void)hipMemsetAsync(agg, 0, (size_t)N * FD * sizeof(float), stream);

  pack_weights<<<576, 256, 0, stream>>>(
      (const float*)d_in[3], (const float*)d_in[5], (const float*)d_in[7],
      (const float*)d_in[11], (const float*)d_in[13], (const float*)d_in[15], wp);
  if (nxbf) cvt_bf16<<<(N * FD / 8 + 255) / 256, 256, 0, stream>>>(node_x, nxbf, N * FD / 8);
  in_edge_kernel<<<(E + 63) / 64, 512, 0, stream>>>(
      node_x, nxbf, edge_attr, eidx, wp,
      (const float*)d_in[4], (const float*)d_in[6], (const float*)d_in[8],
      (const float*)d_in[9], (const float*)d_in[10],
      msg, head, nxt, agg, use_sort, E);
  in_node_kernel<<<(N + 63) / 64, 512, 0, stream>>>(
      node_x, nxbf, msg, head, nxt, agg, wp,
      (const float*)d_in[12], (const float*)d_in[14], (const float*)d_in[16],
      (const float*)d_in[17], (const float*)d_in[18], (float*)d_out, use_sort, N);
}